// Round 1
// baseline (798.222 us; speedup 1.0000x reference)
//
#include <hip/hip_runtime.h>
#include <hip/hip_bf16.h>

#define NN 50000
#define EE 300000
#define ATOM_DIM 128
#define HID 256
#define NODE_DIM 64
#define NUM_LAYERS 3
#define GG 2000
#define LN_EPS 1e-5f

// ---------------- CSR build ----------------

__global__ __launch_bounds__(256) void k_init_cnt(int* cnt, int n) {
    int i = blockIdx.x * 256 + threadIdx.x;
    if (i < n) cnt[i] = 1;  // self-loop
}

__global__ __launch_bounds__(256) void k_count(const int* __restrict__ ei, int* cnt, int e_total) {
    int e = blockIdx.x * 256 + threadIdx.x;
    if (e < e_total) atomicAdd(&cnt[ei[e_total + e]], 1);  // dst = ei[1][e]
}

// two-level exclusive scan over cnt[0..n) -> rowp; chunk = 1024 elements per block
__global__ __launch_bounds__(256) void k_scan1(const int* __restrict__ cnt, int* __restrict__ rowp,
                                               int* __restrict__ csum, int n) {
    __shared__ int s[256];
    int tid = threadIdx.x;
    int base = blockIdx.x * 1024 + tid * 4;
    int v[4];
#pragma unroll
    for (int j = 0; j < 4; ++j) { int i = base + j; v[j] = (i < n) ? cnt[i] : 0; }
    int tsum = v[0] + v[1] + v[2] + v[3];
    s[tid] = tsum;
    __syncthreads();
    for (int off = 1; off < 256; off <<= 1) {
        int t = (tid >= off) ? s[tid - off] : 0;
        __syncthreads();
        s[tid] += t;
        __syncthreads();
    }
    int excl = s[tid] - tsum;
#pragma unroll
    for (int j = 0; j < 4; ++j) { int i = base + j; if (i < n) rowp[i] = excl; excl += v[j]; }
    if (tid == 255) csum[blockIdx.x] = s[255];
}

__global__ __launch_bounds__(256) void k_scan2(int* __restrict__ rowp, int* __restrict__ fill,
                                               const int* __restrict__ csum, int n) {
    __shared__ int soff;
    int chunk = blockIdx.x;
    if (threadIdx.x == 0) {
        int o = 0;
        for (int c = 0; c < chunk; ++c) o += csum[c];
        soff = o;
    }
    __syncthreads();
    int off = soff;
    int base = chunk * 1024 + threadIdx.x * 4;
#pragma unroll
    for (int j = 0; j < 4; ++j) {
        int i = base + j;
        if (i < n) { int r = rowp[i] + off; rowp[i] = r; fill[i] = r; }
    }
    if (chunk == gridDim.x - 1 && threadIdx.x == 255) rowp[n] = off + csum[chunk];
}

__global__ __launch_bounds__(256) void k_dinv(const int* __restrict__ cnt, float* __restrict__ dinv, int n) {
    int i = blockIdx.x * 256 + threadIdx.x;
    if (i < n) dinv[i] = rsqrtf((float)cnt[i]);
}

__global__ __launch_bounds__(256) void k_fill(const int* __restrict__ ei, int* fill, int* __restrict__ csrc,
                                              int e_total, int n) {
    int e = blockIdx.x * 256 + threadIdx.x;
    int tot = e_total + n;
    if (e >= tot) return;
    int s, d;
    if (e < e_total) { s = ei[e]; d = ei[e_total + e]; }
    else { s = d = e - e_total; }
    int pos = atomicAdd(&fill[d], 1);
    csrc[pos] = s;
}

// ---------------- fp32 GEMM: C[M,NC] = A[M,K] @ W[K,NC] (+bias) ----------------
// 128x128 tile, BK=16, 256 threads, 8x8 micro (split quadrants for bank-conflict-free reads)

__global__ __launch_bounds__(256) void k_gemm(const float* __restrict__ A, const float* __restrict__ W,
                                              const float* __restrict__ bias, float* __restrict__ C,
                                              int M, int K, int NC) {
    __shared__ float As[16][132];
    __shared__ float Bs[16][132];
    int tid = threadIdx.x;
    int tx = tid & 15, ty = tid >> 4;
    int row0 = blockIdx.x * 128, col0 = blockIdx.y * 128;
    float acc[8][8] = {};

    int arow = tid >> 2;            // 0..63
    int ac4 = (tid & 3) * 4;        // 0,4,8,12
    int brow = tid >> 5;            // 0..7
    int bc4 = (tid & 31) * 4;       // 0..124

    for (int k0 = 0; k0 < K; k0 += 16) {
#pragma unroll
        for (int half = 0; half < 2; ++half) {
            int r = arow + half * 64;
            int gr = row0 + r;
            float4 v = make_float4(0.f, 0.f, 0.f, 0.f);
            if (gr < M) v = *(const float4*)&A[(size_t)gr * K + k0 + ac4];
            As[ac4 + 0][r] = v.x; As[ac4 + 1][r] = v.y; As[ac4 + 2][r] = v.z; As[ac4 + 3][r] = v.w;
        }
#pragma unroll
        for (int half = 0; half < 2; ++half) {
            int kr = brow + half * 8;
            float4 v = *(const float4*)&W[(size_t)(k0 + kr) * NC + col0 + bc4];
            *(float4*)&Bs[kr][bc4] = v;
        }
        __syncthreads();
#pragma unroll
        for (int kk = 0; kk < 16; ++kk) {
            float a[8], b[8];
            *(float4*)&a[0] = *(const float4*)&As[kk][ty * 4];
            *(float4*)&a[4] = *(const float4*)&As[kk][ty * 4 + 64];
            *(float4*)&b[0] = *(const float4*)&Bs[kk][tx * 4];
            *(float4*)&b[4] = *(const float4*)&Bs[kk][tx * 4 + 64];
#pragma unroll
            for (int i = 0; i < 8; ++i)
#pragma unroll
                for (int j = 0; j < 8; ++j) acc[i][j] += a[i] * b[j];
        }
        __syncthreads();
    }

#pragma unroll
    for (int qi = 0; qi < 2; ++qi)
#pragma unroll
        for (int i = 0; i < 4; ++i) {
            int gr = row0 + qi * 64 + ty * 4 + i;
            if (gr >= M) continue;
#pragma unroll
            for (int qj = 0; qj < 2; ++qj) {
                int gc = col0 + qj * 64 + tx * 4;
                float4 v = make_float4(acc[qi * 4 + i][qj * 4 + 0], acc[qi * 4 + i][qj * 4 + 1],
                                       acc[qi * 4 + i][qj * 4 + 2], acc[qi * 4 + i][qj * 4 + 3]);
                if (bias) { v.x += bias[gc]; v.y += bias[gc + 1]; v.z += bias[gc + 2]; v.w += bias[gc + 3]; }
                *(float4*)&C[(size_t)gr * NC + gc] = v;
            }
        }
}

// ---------------- aggregation: h_out[n] = relu(dinv[n] * sum_{s in in(n)} dinv[s]*hw[s] + b) --------

__global__ __launch_bounds__(256) void k_aggregate(const float* __restrict__ hw, const int* __restrict__ rowp,
                                                   const int* __restrict__ csrc, const float* __restrict__ dinv,
                                                   const float* __restrict__ bias, float* __restrict__ hout, int n) {
    int wave = threadIdx.x >> 6, lane = threadIdx.x & 63;
    int node = blockIdx.x * 4 + wave;
    if (node >= n) return;
    int beg = rowp[node], end = rowp[node + 1];
    int c = lane * 4;
    float4 acc = make_float4(0.f, 0.f, 0.f, 0.f);
    for (int i = beg; i < end; ++i) {
        int s = csrc[i];
        float w = dinv[s];
        float4 r = *(const float4*)&hw[(size_t)s * HID + c];
        acc.x += w * r.x; acc.y += w * r.y; acc.z += w * r.z; acc.w += w * r.w;
    }
    float dn = dinv[node];
    float4 b = *(const float4*)&bias[c];
    float4 o;
    o.x = fmaxf(dn * acc.x + b.x, 0.f);
    o.y = fmaxf(dn * acc.y + b.y, 0.f);
    o.z = fmaxf(dn * acc.z + b.z, 0.f);
    o.w = fmaxf(dn * acc.w + b.w, 0.f);
    *(float4*)&hout[(size_t)node * HID + c] = o;
}

// ---------------- pooling ----------------

__global__ __launch_bounds__(256) void k_pool(const float* __restrict__ h, const int* __restrict__ batch,
                                              float* __restrict__ psum, float* __restrict__ pcnt, int n) {
    int wave = threadIdx.x >> 6, lane = threadIdx.x & 63;
    int node = blockIdx.x * 4 + wave;
    if (node >= n) return;
    int g = batch[node];
    int c = lane * 4;
    float4 v = *(const float4*)&h[(size_t)node * HID + c];
    atomicAdd(&psum[g * HID + c + 0], v.x);
    atomicAdd(&psum[g * HID + c + 1], v.y);
    atomicAdd(&psum[g * HID + c + 2], v.z);
    atomicAdd(&psum[g * HID + c + 3], v.w);
    if (lane == 0) atomicAdd(&pcnt[g], 1.0f);
}

// ---------------- projection + LayerNorm (one wave per graph) ----------------

__global__ __launch_bounds__(256) void k_proj_ln(const float* __restrict__ psum, const float* __restrict__ pcnt,
                                                 const float* __restrict__ Wp, const float* __restrict__ bp,
                                                 const float* __restrict__ gamma, const float* __restrict__ beta,
                                                 float* __restrict__ out, int g_total) {
    int wave = threadIdx.x >> 6, lane = threadIdx.x & 63;
    int g = blockIdx.x * 4 + wave;
    if (g >= g_total) return;
    float inv = 1.0f / fmaxf(pcnt[g], 1.0f);
    float p = bp[lane];
    const float* ms = &psum[(size_t)g * HID];
#pragma unroll 8
    for (int k = 0; k < HID; ++k) {
        p += (ms[k] * inv) * Wp[k * NODE_DIM + lane];
    }
    float sum = p;
#pragma unroll
    for (int m = 1; m < 64; m <<= 1) sum += __shfl_xor(sum, m);
    float mu = sum * (1.0f / 64.0f);
    float d = p - mu;
    float vs = d * d;
#pragma unroll
    for (int m = 1; m < 64; m <<= 1) vs += __shfl_xor(vs, m);
    float var = vs * (1.0f / 64.0f);
    out[(size_t)g * NODE_DIM + lane] = d * rsqrtf(var + LN_EPS) * gamma[lane] + beta[lane];
}

// ---------------- launch ----------------

extern "C" void kernel_launch(void* const* d_in, const int* in_sizes, int n_in,
                              void* d_out, int out_size, void* d_ws, size_t ws_size,
                              hipStream_t stream) {
    const float* x     = (const float*)d_in[0];
    const int*   ei    = (const int*)d_in[1];
    const int*   batch = (const int*)d_in[2];
    const float* W_enc = (const float*)d_in[3];
    const float* b_enc = (const float*)d_in[4];
    const float* Ws    = (const float*)d_in[5];
    const float* bs    = (const float*)d_in[6];
    const float* Wp    = (const float*)d_in[7];
    const float* bp    = (const float*)d_in[8];
    const float* gamma = (const float*)d_in[9];
    const float* beta  = (const float*)d_in[10];
    float* out = (float*)d_out;

    // workspace layout
    float* h    = (float*)d_ws;                 // N*HID
    float* hw   = h + (size_t)NN * HID;         // N*HID
    float* dinv = hw + (size_t)NN * HID;        // N
    float* psum = dinv + NN;                    // G*HID
    float* pcnt = psum + (size_t)GG * HID;      // G
    int* cnt    = (int*)(pcnt + GG);            // N
    int* rowp   = cnt + NN;                     // N+1
    int* fill   = rowp + NN + 1;                // N
    int* csrc   = fill + NN;                    // E+N
    int* csum   = csrc + (EE + NN);             // scan chunk sums (64)

    const int EN = EE + NN;
    const int NCH = (NN + 1023) / 1024;         // 49

    // zero pool accumulators (psum and pcnt are contiguous)
    hipMemsetAsync(psum, 0, (size_t)(GG * HID + GG) * sizeof(float), stream);

    // CSR build
    k_init_cnt<<<(NN + 255) / 256, 256, 0, stream>>>(cnt, NN);
    k_count<<<(EE + 255) / 256, 256, 0, stream>>>(ei, cnt, EE);
    k_scan1<<<NCH, 256, 0, stream>>>(cnt, rowp, csum, NN);
    k_scan2<<<NCH, 256, 0, stream>>>(rowp, fill, csum, NN);
    k_dinv<<<(NN + 255) / 256, 256, 0, stream>>>(cnt, dinv, NN);
    k_fill<<<(EN + 255) / 256, 256, 0, stream>>>(ei, fill, csrc, EE, NN);

    // atom encoder: h = x @ W_enc + b_enc
    {
        dim3 grid((NN + 127) / 128, HID / 128);
        k_gemm<<<grid, 256, 0, stream>>>(x, W_enc, b_enc, h, NN, ATOM_DIM, HID);
    }

    // GCN layers
    for (int l = 0; l < NUM_LAYERS; ++l) {
        dim3 grid((NN + 127) / 128, HID / 128);
        k_gemm<<<grid, 256, 0, stream>>>(h, Ws + (size_t)l * HID * HID, nullptr, hw, NN, HID, HID);
        k_aggregate<<<(NN + 3) / 4, 256, 0, stream>>>(hw, rowp, csrc, dinv, bs + (size_t)l * HID, h, NN);
    }

    // global mean pool
    k_pool<<<(NN + 3) / 4, 256, 0, stream>>>(h, batch, psum, pcnt, NN);

    // projection + LayerNorm
    k_proj_ln<<<(GG + 3) / 4, 256, 0, stream>>>(psum, pcnt, Wp, bp, gamma, beta, out, GG);
}

// Round 2
// 617.879 us; speedup vs baseline: 1.2919x; 1.2919x over previous
//
#include <hip/hip_runtime.h>
#include <hip/hip_bf16.h>

#define NN 50000
#define EE 300000
#define ATOM_DIM 128
#define HID 256
#define NODE_DIM 64
#define NUM_LAYERS 3
#define GG 2000
#define LN_EPS 1e-5f

// ---------------- CSR build ----------------

__global__ __launch_bounds__(256) void k_init_cnt(int* cnt, int n) {
    int i = blockIdx.x * 256 + threadIdx.x;
    if (i < n) cnt[i] = 1;  // self-loop
}

__global__ __launch_bounds__(256) void k_count(const int* __restrict__ ei, int* cnt, int e_total) {
    int e = blockIdx.x * 256 + threadIdx.x;
    if (e < e_total) atomicAdd(&cnt[ei[e_total + e]], 1);  // dst = ei[1][e]
}

// two-level exclusive scan over cnt[0..n) -> rowp; chunk = 1024 elements per block
__global__ __launch_bounds__(256) void k_scan1(const int* __restrict__ cnt, int* __restrict__ rowp,
                                               int* __restrict__ csum, int n) {
    __shared__ int s[256];
    int tid = threadIdx.x;
    int base = blockIdx.x * 1024 + tid * 4;
    int v[4];
#pragma unroll
    for (int j = 0; j < 4; ++j) { int i = base + j; v[j] = (i < n) ? cnt[i] : 0; }
    int tsum = v[0] + v[1] + v[2] + v[3];
    s[tid] = tsum;
    __syncthreads();
    for (int off = 1; off < 256; off <<= 1) {
        int t = (tid >= off) ? s[tid - off] : 0;
        __syncthreads();
        s[tid] += t;
        __syncthreads();
    }
    int excl = s[tid] - tsum;
#pragma unroll
    for (int j = 0; j < 4; ++j) { int i = base + j; if (i < n) rowp[i] = excl; excl += v[j]; }
    if (tid == 255) csum[blockIdx.x] = s[255];
}

__global__ __launch_bounds__(256) void k_scan2(int* __restrict__ rowp, int* __restrict__ fill,
                                               const int* __restrict__ csum, int n) {
    __shared__ int soff;
    int chunk = blockIdx.x;
    if (threadIdx.x == 0) {
        int o = 0;
        for (int c = 0; c < chunk; ++c) o += csum[c];
        soff = o;
    }
    __syncthreads();
    int off = soff;
    int base = chunk * 1024 + threadIdx.x * 4;
#pragma unroll
    for (int j = 0; j < 4; ++j) {
        int i = base + j;
        if (i < n) { int r = rowp[i] + off; rowp[i] = r; fill[i] = r; }
    }
    if (chunk == gridDim.x - 1 && threadIdx.x == 255) rowp[n] = off + csum[chunk];
}

__global__ __launch_bounds__(256) void k_dinv(const int* __restrict__ cnt, float* __restrict__ dinv, int n) {
    int i = blockIdx.x * 256 + threadIdx.x;
    if (i < n) dinv[i] = rsqrtf((float)cnt[i]);
}

__global__ __launch_bounds__(256) void k_fill(const int* __restrict__ ei, int* fill, int* __restrict__ csrc,
                                              int e_total, int n) {
    int e = blockIdx.x * 256 + threadIdx.x;
    int tot = e_total + n;
    if (e >= tot) return;
    int s, d;
    if (e < e_total) { s = ei[e]; d = ei[e_total + e]; }
    else { s = d = e - e_total; }
    int pos = atomicAdd(&fill[d], 1);
    csrc[pos] = s;
}

// graph boundaries: gstart[g] = lower_bound(batch, g), g in [0, G]
__global__ __launch_bounds__(256) void k_gbound(const int* __restrict__ batch, int* __restrict__ gstart,
                                                int n, int g_total) {
    int g = blockIdx.x * 256 + threadIdx.x;
    if (g > g_total) return;
    int lo = 0, hi = n;
    while (lo < hi) { int mid = (lo + hi) >> 1; if (batch[mid] < g) lo = mid + 1; else hi = mid; }
    gstart[g] = lo;
}

// ---------------- fp32 GEMM: C[M,NC] = A[M,K] @ W[K,NC] (+bias) ----------------
// 128x128 tile, BK=16, 256 threads, 8x8 micro (split quadrants for bank-conflict-free reads)

__global__ __launch_bounds__(256) void k_gemm(const float* __restrict__ A, const float* __restrict__ W,
                                              const float* __restrict__ bias, float* __restrict__ C,
                                              int M, int K, int NC) {
    __shared__ float As[16][132];
    __shared__ float Bs[16][132];
    int tid = threadIdx.x;
    int tx = tid & 15, ty = tid >> 4;
    int row0 = blockIdx.x * 128, col0 = blockIdx.y * 128;
    float acc[8][8] = {};

    int arow = tid >> 2;            // 0..63
    int ac4 = (tid & 3) * 4;        // 0,4,8,12
    int brow = tid >> 5;            // 0..7
    int bc4 = (tid & 31) * 4;       // 0..124

    for (int k0 = 0; k0 < K; k0 += 16) {
#pragma unroll
        for (int half = 0; half < 2; ++half) {
            int r = arow + half * 64;
            int gr = row0 + r;
            float4 v = make_float4(0.f, 0.f, 0.f, 0.f);
            if (gr < M) v = *(const float4*)&A[(size_t)gr * K + k0 + ac4];
            As[ac4 + 0][r] = v.x; As[ac4 + 1][r] = v.y; As[ac4 + 2][r] = v.z; As[ac4 + 3][r] = v.w;
        }
#pragma unroll
        for (int half = 0; half < 2; ++half) {
            int kr = brow + half * 8;
            float4 v = *(const float4*)&W[(size_t)(k0 + kr) * NC + col0 + bc4];
            *(float4*)&Bs[kr][bc4] = v;
        }
        __syncthreads();
#pragma unroll
        for (int kk = 0; kk < 16; ++kk) {
            float a[8], b[8];
            *(float4*)&a[0] = *(const float4*)&As[kk][ty * 4];
            *(float4*)&a[4] = *(const float4*)&As[kk][ty * 4 + 64];
            *(float4*)&b[0] = *(const float4*)&Bs[kk][tx * 4];
            *(float4*)&b[4] = *(const float4*)&Bs[kk][tx * 4 + 64];
#pragma unroll
            for (int i = 0; i < 8; ++i)
#pragma unroll
                for (int j = 0; j < 8; ++j) acc[i][j] += a[i] * b[j];
        }
        __syncthreads();
    }

#pragma unroll
    for (int qi = 0; qi < 2; ++qi)
#pragma unroll
        for (int i = 0; i < 4; ++i) {
            int gr = row0 + qi * 64 + ty * 4 + i;
            if (gr >= M) continue;
#pragma unroll
            for (int qj = 0; qj < 2; ++qj) {
                int gc = col0 + qj * 64 + tx * 4;
                float4 v = make_float4(acc[qi * 4 + i][qj * 4 + 0], acc[qi * 4 + i][qj * 4 + 1],
                                       acc[qi * 4 + i][qj * 4 + 2], acc[qi * 4 + i][qj * 4 + 3]);
                if (bias) { v.x += bias[gc]; v.y += bias[gc + 1]; v.z += bias[gc + 2]; v.w += bias[gc + 3]; }
                *(float4*)&C[(size_t)gr * NC + gc] = v;
            }
        }
}

// ---------------- aggregation: h_out[n] = relu(dinv[n] * sum_{s in in(n)} dinv[s]*hw[s] + b) --------

__global__ __launch_bounds__(256) void k_aggregate(const float* __restrict__ hw, const int* __restrict__ rowp,
                                                   const int* __restrict__ csrc, const float* __restrict__ dinv,
                                                   const float* __restrict__ bias, float* __restrict__ hout, int n) {
    int wave = threadIdx.x >> 6, lane = threadIdx.x & 63;
    int node = blockIdx.x * 4 + wave;
    if (node >= n) return;
    int beg = rowp[node], end = rowp[node + 1];
    int c = lane * 4;
    float4 acc = make_float4(0.f, 0.f, 0.f, 0.f);
    for (int i = beg; i < end; ++i) {
        int s = csrc[i];
        float w = dinv[s];
        float4 r = *(const float4*)&hw[(size_t)s * HID + c];
        acc.x += w * r.x; acc.y += w * r.y; acc.z += w * r.z; acc.w += w * r.w;
    }
    float dn = dinv[node];
    float4 b = *(const float4*)&bias[c];
    float4 o;
    o.x = fmaxf(dn * acc.x + b.x, 0.f);
    o.y = fmaxf(dn * acc.y + b.y, 0.f);
    o.z = fmaxf(dn * acc.z + b.z, 0.f);
    o.w = fmaxf(dn * acc.w + b.w, 0.f);
    *(float4*)&hout[(size_t)node * HID + c] = o;
}

// ---------------- fused pool + projection + LayerNorm (one block per graph) ----------------

__global__ __launch_bounds__(256) void k_pool_proj_ln(const float* __restrict__ h, const int* __restrict__ gstart,
                                                      const float* __restrict__ Wp, const float* __restrict__ bp,
                                                      const float* __restrict__ gamma, const float* __restrict__ beta,
                                                      float* __restrict__ out) {
    __shared__ float mol[HID];
    __shared__ float part[4][NODE_DIM];
    int g = blockIdx.x;
    int t = threadIdx.x;
    int beg = gstart[g], end = gstart[g + 1];
    // mean-pool: thread t owns column t; rows are contiguous -> coalesced
    float sum = 0.f;
    for (int r = beg; r < end; ++r) sum += h[(size_t)r * HID + t];
    float inv = 1.0f / fmaxf((float)(end - beg), 1.0f);
    mol[t] = sum * inv;
    __syncthreads();
    // projection: wave w handles k-range [w*64, w*64+64), lane j = output col
    int w = t >> 6, j = t & 63;
    float p = 0.f;
    int k0 = w * 64;
#pragma unroll 8
    for (int k = 0; k < 64; ++k) p += mol[k0 + k] * Wp[(size_t)(k0 + k) * NODE_DIM + j];
    part[w][j] = p;
    __syncthreads();
    if (t < 64) {
        float pj = part[0][j] + part[1][j] + part[2][j] + part[3][j] + bp[j];
        float s = pj;
#pragma unroll
        for (int m = 1; m < 64; m <<= 1) s += __shfl_xor(s, m);
        float mu = s * (1.0f / 64.0f);
        float d = pj - mu;
        float vs = d * d;
#pragma unroll
        for (int m = 1; m < 64; m <<= 1) vs += __shfl_xor(vs, m);
        out[(size_t)g * NODE_DIM + j] = d * rsqrtf(vs * (1.0f / 64.0f) + LN_EPS) * gamma[j] + beta[j];
    }
}

// ---------------- launch ----------------

extern "C" void kernel_launch(void* const* d_in, const int* in_sizes, int n_in,
                              void* d_out, int out_size, void* d_ws, size_t ws_size,
                              hipStream_t stream) {
    const float* x     = (const float*)d_in[0];
    const int*   ei    = (const int*)d_in[1];
    const int*   batch = (const int*)d_in[2];
    const float* W_enc = (const float*)d_in[3];
    const float* b_enc = (const float*)d_in[4];
    const float* Ws    = (const float*)d_in[5];
    const float* bs    = (const float*)d_in[6];
    const float* Wp    = (const float*)d_in[7];
    const float* bp    = (const float*)d_in[8];
    const float* gamma = (const float*)d_in[9];
    const float* beta  = (const float*)d_in[10];
    float* out = (float*)d_out;

    // workspace layout
    float* h    = (float*)d_ws;                 // N*HID
    float* hw   = h + (size_t)NN * HID;         // N*HID
    float* dinv = hw + (size_t)NN * HID;        // N
    int* cnt    = (int*)(dinv + NN);            // N
    int* rowp   = cnt + NN;                     // N+1
    int* fill   = rowp + NN + 1;                // N
    int* csrc   = fill + NN;                    // E+N
    int* csum   = csrc + (EE + NN);             // scan chunk sums (64)
    int* gstart = csum + 64;                    // G+1

    const int EN = EE + NN;
    const int NCH = (NN + 1023) / 1024;         // 49

    // CSR build + graph boundaries
    k_init_cnt<<<(NN + 255) / 256, 256, 0, stream>>>(cnt, NN);
    k_count<<<(EE + 255) / 256, 256, 0, stream>>>(ei, cnt, EE);
    k_scan1<<<NCH, 256, 0, stream>>>(cnt, rowp, csum, NN);
    k_scan2<<<NCH, 256, 0, stream>>>(rowp, fill, csum, NN);
    k_dinv<<<(NN + 255) / 256, 256, 0, stream>>>(cnt, dinv, NN);
    k_fill<<<(EN + 255) / 256, 256, 0, stream>>>(ei, fill, csrc, EE, NN);
    k_gbound<<<(GG + 1 + 255) / 256, 256, 0, stream>>>(batch, gstart, NN, GG);

    // atom encoder: h = x @ W_enc + b_enc
    {
        dim3 grid((NN + 127) / 128, HID / 128);
        k_gemm<<<grid, 256, 0, stream>>>(x, W_enc, b_enc, h, NN, ATOM_DIM, HID);
    }

    // GCN layers
    for (int l = 0; l < NUM_LAYERS; ++l) {
        dim3 grid((NN + 127) / 128, HID / 128);
        k_gemm<<<grid, 256, 0, stream>>>(h, Ws + (size_t)l * HID * HID, nullptr, hw, NN, HID, HID);
        k_aggregate<<<(NN + 3) / 4, 256, 0, stream>>>(hw, rowp, csrc, dinv, bs + (size_t)l * HID, h, NN);
    }

    // fused global-mean-pool + projection + LayerNorm
    k_pool_proj_ln<<<GG, 256, 0, stream>>>(h, gstart, Wp, bp, gamma, beta, out);
}

// Round 3
// 362.379 us; speedup vs baseline: 2.2027x; 1.7051x over previous
//
#include <hip/hip_runtime.h>
#include <hip/hip_bf16.h>

#define NN 50000
#define EE 300000
#define ATOM_DIM 128
#define HID 256
#define NODE_DIM 64
#define NUM_LAYERS 3
#define GG 2000
#define LN_EPS 1e-5f

typedef __attribute__((ext_vector_type(8))) short bf16x8;
typedef __attribute__((ext_vector_type(4))) float f32x4;

__device__ __forceinline__ ushort f2bf(float f) {
    __hip_bfloat16 h = __float2bfloat16(f);
    return *reinterpret_cast<ushort*>(&h);
}
__device__ __forceinline__ float bf2f(ushort u) {
    __hip_bfloat16 h = *reinterpret_cast<__hip_bfloat16*>(&u);
    return __bfloat162float(h);
}

__device__ __forceinline__ void gll16(const void* g, void* l) {
    __builtin_amdgcn_global_load_lds((const __attribute__((address_space(1))) unsigned int*)g,
                                     (__attribute__((address_space(3))) unsigned int*)l, 16, 0, 0);
}

// ---------------- CSR build ----------------

__global__ __launch_bounds__(256) void k_init_cnt(int* cnt, int n) {
    int i = blockIdx.x * 256 + threadIdx.x;
    if (i < n) cnt[i] = 1;  // self-loop
}

__global__ __launch_bounds__(256) void k_count(const int* __restrict__ ei, int* cnt, int e_total) {
    int e = blockIdx.x * 256 + threadIdx.x;
    if (e < e_total) atomicAdd(&cnt[ei[e_total + e]], 1);  // dst = ei[1][e]
}

__global__ __launch_bounds__(256) void k_scan1(const int* __restrict__ cnt, int* __restrict__ rowp,
                                               int* __restrict__ csum, int n) {
    __shared__ int s[256];
    int tid = threadIdx.x;
    int base = blockIdx.x * 1024 + tid * 4;
    int v[4];
#pragma unroll
    for (int j = 0; j < 4; ++j) { int i = base + j; v[j] = (i < n) ? cnt[i] : 0; }
    int tsum = v[0] + v[1] + v[2] + v[3];
    s[tid] = tsum;
    __syncthreads();
    for (int off = 1; off < 256; off <<= 1) {
        int t = (tid >= off) ? s[tid - off] : 0;
        __syncthreads();
        s[tid] += t;
        __syncthreads();
    }
    int excl = s[tid] - tsum;
#pragma unroll
    for (int j = 0; j < 4; ++j) { int i = base + j; if (i < n) rowp[i] = excl; excl += v[j]; }
    if (tid == 255) csum[blockIdx.x] = s[255];
}

__global__ __launch_bounds__(256) void k_scan2(int* __restrict__ rowp, int* __restrict__ fill,
                                               const int* __restrict__ csum, int n) {
    __shared__ int soff;
    int chunk = blockIdx.x;
    if (threadIdx.x == 0) {
        int o = 0;
        for (int c = 0; c < chunk; ++c) o += csum[c];
        soff = o;
    }
    __syncthreads();
    int off = soff;
    int base = chunk * 1024 + threadIdx.x * 4;
#pragma unroll
    for (int j = 0; j < 4; ++j) {
        int i = base + j;
        if (i < n) { int r = rowp[i] + off; rowp[i] = r; fill[i] = r; }
    }
    if (chunk == gridDim.x - 1 && threadIdx.x == 255) rowp[n] = off + csum[chunk];
}

__global__ __launch_bounds__(256) void k_dinv(const int* __restrict__ cnt, float* __restrict__ dinv, int n) {
    int i = blockIdx.x * 256 + threadIdx.x;
    if (i < n) dinv[i] = rsqrtf((float)cnt[i]);
}

__global__ __launch_bounds__(256) void k_fill(const int* __restrict__ ei, int* fill, int* __restrict__ csrc,
                                              int e_total, int n) {
    int e = blockIdx.x * 256 + threadIdx.x;
    int tot = e_total + n;
    if (e >= tot) return;
    int s, d;
    if (e < e_total) { s = ei[e]; d = ei[e_total + e]; }
    else { s = d = e - e_total; }
    int pos = atomicAdd(&fill[d], 1);
    csrc[pos] = s;
}

__global__ __launch_bounds__(256) void k_gbound(const int* __restrict__ batch, int* __restrict__ gstart,
                                                int n, int g_total) {
    int g = blockIdx.x * 256 + threadIdx.x;
    if (g > g_total) return;
    int lo = 0, hi = n;
    while (lo < hi) { int mid = (lo + hi) >> 1; if (batch[mid] < g) lo = mid + 1; else hi = mid; }
    gstart[g] = lo;
}

// ---------------- fp32 -> bf16 convert ----------------

__global__ __launch_bounds__(256) void k_cvt(const float* __restrict__ in, ushort* __restrict__ out, int n) {
    int i = (blockIdx.x * 256 + threadIdx.x) * 4;
    if (i >= n) return;
    float4 v = *(const float4*)&in[i];
    ushort4 o;
    o.x = f2bf(v.x); o.y = f2bf(v.y); o.z = f2bf(v.z); o.w = f2bf(v.w);
    *(ushort4*)&out[i] = o;
}

// ---------------- weight transpose + convert: Wt[n][k] = bf16(W[k][n]) ----------------

__global__ __launch_bounds__(256) void k_wt(const float* __restrict__ W, ushort* __restrict__ Wt, int K, int N) {
    __shared__ float t[32][33];
    int bx = blockIdx.x;  // along N
    int by = blockIdx.y;  // along K
    int lx = threadIdx.x & 31, ly = threadIdx.x >> 5;  // 32x8
#pragma unroll
    for (int s = 0; s < 32; s += 8)
        t[ly + s][lx] = W[(size_t)(by * 32 + ly + s) * N + bx * 32 + lx];
    __syncthreads();
#pragma unroll
    for (int s = 0; s < 32; s += 8)
        Wt[(size_t)(bx * 32 + ly + s) * K + by * 32 + lx] = f2bf(t[lx][ly + s]);
}

// ---------------- bf16 MFMA GEMM: C[M,NC] = A[M,K] @ Bt[NC,K]^T (+bias) ----------------
// 128x128 tile, BK=32, 4 waves (2x2), each wave 64x64 = 4x4 frags of 16x16x32.
// LDS tiles [128][32] bf16, seg-swizzled: LDS slot c holds global seg c ^ ((row>>1)&3).

__global__ __launch_bounds__(256) void k_gemm_bf16(const ushort* __restrict__ A, const ushort* __restrict__ Bt,
                                                   const float* __restrict__ bias, float* __restrict__ Cf,
                                                   ushort* __restrict__ Cb, int M, int K, int NC) {
    __shared__ short As[4096];  // 128 rows x 32 bf16
    __shared__ short Bs[4096];
    int tid = threadIdx.x;
    int lane = tid & 63, w = tid >> 6;
    int wr = w >> 1, wc = w & 1;
    int row0 = blockIdx.x * 128, col0 = blockIdx.y * 128;

    f32x4 acc[4][4] = {};

    int r15 = lane & 15;
    int swz = ((r15 >> 1) & 3) << 3;           // read-side XOR, in shorts
    int kseg = (lane >> 4) << 3;               // k seg this lane needs (8 bf16)
    int koff = kseg ^ swz;

    // staging geometry (same for A and B tiles)
    int st_row[2], st_cg[2];
#pragma unroll
    for (int i = 0; i < 2; ++i) {
        int row = i * 64 + (tid >> 2);
        st_row[i] = row;
        st_cg[i] = (tid & 3) ^ ((row >> 1) & 3);
    }

    for (int k0 = 0; k0 < K; k0 += 32) {
#pragma unroll
        for (int i = 0; i < 2; ++i) {
            int ra = row0 + st_row[i];
            if (ra > M - 1) ra = M - 1;
            gll16(A + (size_t)ra * K + k0 + st_cg[i] * 8, &As[i * 2048 + w * 512]);
            gll16(Bt + (size_t)(col0 + st_row[i]) * K + k0 + st_cg[i] * 8, &Bs[i * 2048 + w * 512]);
        }
        __syncthreads();
        bf16x8 af[4], bfr[4];
#pragma unroll
        for (int m = 0; m < 4; ++m) af[m] = *(const bf16x8*)&As[(wr * 64 + m * 16 + r15) * 32 + koff];
#pragma unroll
        for (int n = 0; n < 4; ++n) bfr[n] = *(const bf16x8*)&Bs[(wc * 64 + n * 16 + r15) * 32 + koff];
#pragma unroll
        for (int m = 0; m < 4; ++m)
#pragma unroll
            for (int n = 0; n < 4; ++n)
                acc[m][n] = __builtin_amdgcn_mfma_f32_16x16x32_bf16(af[m], bfr[n], acc[m][n], 0, 0, 0);
        __syncthreads();
    }

    // epilogue: C/D layout col = lane&15, row = (lane>>4)*4 + r
    int cc = lane & 15, rq = (lane >> 4) * 4;
#pragma unroll
    for (int m = 0; m < 4; ++m) {
#pragma unroll
        for (int r = 0; r < 4; ++r) {
            int gr = row0 + wr * 64 + m * 16 + rq + r;
            if (gr >= M) continue;
#pragma unroll
            for (int n = 0; n < 4; ++n) {
                int gc = col0 + wc * 64 + n * 16 + cc;
                float v = acc[m][n][r];
                if (bias) v += bias[gc];
                if (Cf) Cf[(size_t)gr * NC + gc] = v;
                if (Cb) Cb[(size_t)gr * NC + gc] = f2bf(v);
            }
        }
    }
}

// ---------------- aggregation: hbf[n] = bf16(relu(dinv[n] * sum dinv[s]*hw[s] + b)) ----------------

__global__ __launch_bounds__(256) void k_aggregate(const float* __restrict__ hw, const int* __restrict__ rowp,
                                                   const int* __restrict__ csrc, const float* __restrict__ dinv,
                                                   const float* __restrict__ bias, ushort* __restrict__ hbf, int n) {
    int wave = threadIdx.x >> 6, lane = threadIdx.x & 63;
    int node = blockIdx.x * 4 + wave;
    if (node >= n) return;
    int beg = rowp[node], end = rowp[node + 1];
    int c = lane * 4;
    float4 acc = make_float4(0.f, 0.f, 0.f, 0.f);
    for (int i = beg; i < end; ++i) {
        int s = csrc[i];
        float w = dinv[s];
        float4 r = *(const float4*)&hw[(size_t)s * HID + c];
        acc.x += w * r.x; acc.y += w * r.y; acc.z += w * r.z; acc.w += w * r.w;
    }
    float dn = dinv[node];
    float4 b = *(const float4*)&bias[c];
    ushort4 o;
    o.x = f2bf(fmaxf(dn * acc.x + b.x, 0.f));
    o.y = f2bf(fmaxf(dn * acc.y + b.y, 0.f));
    o.z = f2bf(fmaxf(dn * acc.z + b.z, 0.f));
    o.w = f2bf(fmaxf(dn * acc.w + b.w, 0.f));
    *(ushort4*)&hbf[(size_t)node * HID + c] = o;
}

// ---------------- fused pool + projection + LayerNorm (one block per graph) ----------------

__global__ __launch_bounds__(256) void k_pool_proj_ln(const ushort* __restrict__ hbf, const int* __restrict__ gstart,
                                                      const float* __restrict__ Wp, const float* __restrict__ bp,
                                                      const float* __restrict__ gamma, const float* __restrict__ beta,
                                                      float* __restrict__ out) {
    __shared__ float mol[HID];
    __shared__ float part[4][NODE_DIM];
    int g = blockIdx.x;
    int t = threadIdx.x;
    int beg = gstart[g], end = gstart[g + 1];
    float sum = 0.f;
    for (int r = beg; r < end; ++r) sum += bf2f(hbf[(size_t)r * HID + t]);
    float inv = 1.0f / fmaxf((float)(end - beg), 1.0f);
    mol[t] = sum * inv;
    __syncthreads();
    int w = t >> 6, j = t & 63;
    float p = 0.f;
    int k0 = w * 64;
#pragma unroll 8
    for (int k = 0; k < 64; ++k) p += mol[k0 + k] * Wp[(size_t)(k0 + k) * NODE_DIM + j];
    part[w][j] = p;
    __syncthreads();
    if (t < 64) {
        float pj = part[0][j] + part[1][j] + part[2][j] + part[3][j] + bp[j];
        float s = pj;
#pragma unroll
        for (int m = 1; m < 64; m <<= 1) s += __shfl_xor(s, m);
        float mu = s * (1.0f / 64.0f);
        float d = pj - mu;
        float vs = d * d;
#pragma unroll
        for (int m = 1; m < 64; m <<= 1) vs += __shfl_xor(vs, m);
        out[(size_t)g * NODE_DIM + j] = d * rsqrtf(vs * (1.0f / 64.0f) + LN_EPS) * gamma[j] + beta[j];
    }
}

// ---------------- launch ----------------

extern "C" void kernel_launch(void* const* d_in, const int* in_sizes, int n_in,
                              void* d_out, int out_size, void* d_ws, size_t ws_size,
                              hipStream_t stream) {
    const float* x     = (const float*)d_in[0];
    const int*   ei    = (const int*)d_in[1];
    const int*   batch = (const int*)d_in[2];
    const float* W_enc = (const float*)d_in[3];
    const float* b_enc = (const float*)d_in[4];
    const float* Ws    = (const float*)d_in[5];
    const float* bs    = (const float*)d_in[6];
    const float* Wp    = (const float*)d_in[7];
    const float* bp    = (const float*)d_in[8];
    const float* gamma = (const float*)d_in[9];
    const float* beta  = (const float*)d_in[10];
    float* out = (float*)d_out;

    // workspace layout
    float*  hw   = (float*)d_ws;                       // N*HID f32
    ushort* hbf  = (ushort*)(hw + (size_t)NN * HID);   // N*HID bf16
    ushort* xbf  = hbf + (size_t)NN * HID;             // N*ATOM_DIM bf16
    ushort* wtE  = xbf + (size_t)NN * ATOM_DIM;        // 256*128 (W_enc^T)
    ushort* wtL  = wtE + HID * ATOM_DIM;               // 3 * 256*256 (Ws^T)
    float*  dinv = (float*)(wtL + (size_t)NUM_LAYERS * HID * HID);  // N
    int* cnt    = (int*)(dinv + NN);                   // N
    int* rowp   = cnt + NN;                            // N+1
    int* fill   = rowp + NN + 1;                       // N
    int* csrc   = fill + NN;                           // E+N
    int* csum   = csrc + (EE + NN);                    // 64
    int* gstart = csum + 64;                           // G+1

    const int EN = EE + NN;
    const int NCH = (NN + 1023) / 1024;

    // input conversions
    k_cvt<<<(NN * ATOM_DIM / 4 + 255) / 256, 256, 0, stream>>>(x, xbf, NN * ATOM_DIM);
    {
        dim3 gE(HID / 32, ATOM_DIM / 32);
        k_wt<<<gE, 256, 0, stream>>>(W_enc, wtE, ATOM_DIM, HID);
        dim3 gL(HID / 32, HID / 32);
        for (int l = 0; l < NUM_LAYERS; ++l)
            k_wt<<<gL, 256, 0, stream>>>(Ws + (size_t)l * HID * HID, wtL + (size_t)l * HID * HID, HID, HID);
    }

    // CSR build + graph boundaries
    k_init_cnt<<<(NN + 255) / 256, 256, 0, stream>>>(cnt, NN);
    k_count<<<(EE + 255) / 256, 256, 0, stream>>>(ei, cnt, EE);
    k_scan1<<<NCH, 256, 0, stream>>>(cnt, rowp, csum, NN);
    k_scan2<<<NCH, 256, 0, stream>>>(rowp, fill, csum, NN);
    k_dinv<<<(NN + 255) / 256, 256, 0, stream>>>(cnt, dinv, NN);
    k_fill<<<(EN + 255) / 256, 256, 0, stream>>>(ei, fill, csrc, EE, NN);
    k_gbound<<<(GG + 1 + 255) / 256, 256, 0, stream>>>(batch, gstart, NN, GG);

    dim3 ggrid((NN + 127) / 128, HID / 128);

    // atom encoder: h_bf = bf16(x @ W_enc + b_enc)
    k_gemm_bf16<<<ggrid, 256, 0, stream>>>(xbf, wtE, b_enc, nullptr, hbf, NN, ATOM_DIM, HID);

    // GCN layers
    for (int l = 0; l < NUM_LAYERS; ++l) {
        k_gemm_bf16<<<ggrid, 256, 0, stream>>>(hbf, wtL + (size_t)l * HID * HID, nullptr, hw, nullptr, NN, HID, HID);
        k_aggregate<<<(NN + 3) / 4, 256, 0, stream>>>(hw, rowp, csrc, dinv, bs + (size_t)l * HID, hbf, NN);
    }

    // fused global-mean-pool + projection + LayerNorm
    k_pool_proj_ln<<<GG, 256, 0, stream>>>(hbf, gstart, Wp, bp, gamma, beta, out);
}

// Round 4
// 360.853 us; speedup vs baseline: 2.2120x; 1.0042x over previous
//
#include <hip/hip_runtime.h>
#include <hip/hip_bf16.h>

#define NN 50000
#define EE 300000
#define ATOM_DIM 128
#define HID 256
#define NODE_DIM 64
#define NUM_LAYERS 3
#define GG 2000
#define LN_EPS 1e-5f

typedef __attribute__((ext_vector_type(8))) short bf16x8;
typedef __attribute__((ext_vector_type(4))) float f32x4;

__device__ __forceinline__ ushort f2bf(float f) {
    __hip_bfloat16 h = __float2bfloat16(f);
    return *reinterpret_cast<ushort*>(&h);
}
__device__ __forceinline__ float bf2f(ushort u) {
    __hip_bfloat16 h = *reinterpret_cast<__hip_bfloat16*>(&u);
    return __bfloat162float(h);
}

__device__ __forceinline__ void gll16(const void* g, void* l) {
    __builtin_amdgcn_global_load_lds((const __attribute__((address_space(1))) unsigned int*)g,
                                     (__attribute__((address_space(3))) unsigned int*)l, 16, 0, 0);
}

// ---------------- CSR build ----------------

__global__ __launch_bounds__(256) void k_init_cnt(int* cnt, int n) {
    int i = blockIdx.x * 256 + threadIdx.x;
    if (i < n) cnt[i] = 1;  // self-loop
}

__global__ __launch_bounds__(256) void k_count(const int* __restrict__ ei, int* cnt, int e_total) {
    int e = blockIdx.x * 256 + threadIdx.x;
    if (e < e_total) atomicAdd(&cnt[ei[e_total + e]], 1);  // dst = ei[1][e]
}

__global__ __launch_bounds__(256) void k_scan1(const int* __restrict__ cnt, int* __restrict__ rowp,
                                               int* __restrict__ csum, int n) {
    __shared__ int s[256];
    int tid = threadIdx.x;
    int base = blockIdx.x * 1024 + tid * 4;
    int v[4];
#pragma unroll
    for (int j = 0; j < 4; ++j) { int i = base + j; v[j] = (i < n) ? cnt[i] : 0; }
    int tsum = v[0] + v[1] + v[2] + v[3];
    s[tid] = tsum;
    __syncthreads();
    for (int off = 1; off < 256; off <<= 1) {
        int t = (tid >= off) ? s[tid - off] : 0;
        __syncthreads();
        s[tid] += t;
        __syncthreads();
    }
    int excl = s[tid] - tsum;
#pragma unroll
    for (int j = 0; j < 4; ++j) { int i = base + j; if (i < n) rowp[i] = excl; excl += v[j]; }
    if (tid == 255) csum[blockIdx.x] = s[255];
}

__global__ __launch_bounds__(256) void k_scan2(int* __restrict__ rowp, int* __restrict__ fill,
                                               const int* __restrict__ csum, int n) {
    __shared__ int soff;
    int chunk = blockIdx.x;
    if (threadIdx.x == 0) {
        int o = 0;
        for (int c = 0; c < chunk; ++c) o += csum[c];
        soff = o;
    }
    __syncthreads();
    int off = soff;
    int base = chunk * 1024 + threadIdx.x * 4;
#pragma unroll
    for (int j = 0; j < 4; ++j) {
        int i = base + j;
        if (i < n) { int r = rowp[i] + off; rowp[i] = r; fill[i] = r; }
    }
    if (chunk == gridDim.x - 1 && threadIdx.x == 255) rowp[n] = off + csum[chunk];
}

__global__ __launch_bounds__(256) void k_dinv(const int* __restrict__ cnt, float* __restrict__ dinv, int n) {
    int i = blockIdx.x * 256 + threadIdx.x;
    if (i < n) dinv[i] = rsqrtf((float)cnt[i]);
}

__global__ __launch_bounds__(256) void k_fill(const int* __restrict__ ei, int* fill, int* __restrict__ csrc,
                                              int e_total, int n) {
    int e = blockIdx.x * 256 + threadIdx.x;
    int tot = e_total + n;
    if (e >= tot) return;
    int s, d;
    if (e < e_total) { s = ei[e]; d = ei[e_total + e]; }
    else { s = d = e - e_total; }
    int pos = atomicAdd(&fill[d], 1);
    csrc[pos] = s;
}

__global__ __launch_bounds__(256) void k_gbound(const int* __restrict__ batch, int* __restrict__ gstart,
                                                int n, int g_total) {
    int g = blockIdx.x * 256 + threadIdx.x;
    if (g > g_total) return;
    int lo = 0, hi = n;
    while (lo < hi) { int mid = (lo + hi) >> 1; if (batch[mid] < g) lo = mid + 1; else hi = mid; }
    gstart[g] = lo;
}

// ---------------- fp32 -> bf16 convert ----------------

__global__ __launch_bounds__(256) void k_cvt(const float* __restrict__ in, ushort* __restrict__ out, int n) {
    int i = (blockIdx.x * 256 + threadIdx.x) * 4;
    if (i >= n) return;
    float4 v = *(const float4*)&in[i];
    ushort4 o;
    o.x = f2bf(v.x); o.y = f2bf(v.y); o.z = f2bf(v.z); o.w = f2bf(v.w);
    *(ushort4*)&out[i] = o;
}

// ---------------- weight transpose + convert: Wt[n][k] = bf16(W[k][n]) ----------------

__global__ __launch_bounds__(256) void k_wt(const float* __restrict__ W, ushort* __restrict__ Wt, int K, int N) {
    __shared__ float t[32][33];
    int bx = blockIdx.x;  // along N
    int by = blockIdx.y;  // along K
    int lx = threadIdx.x & 31, ly = threadIdx.x >> 5;  // 32x8
#pragma unroll
    for (int s = 0; s < 32; s += 8)
        t[ly + s][lx] = W[(size_t)(by * 32 + ly + s) * N + bx * 32 + lx];
    __syncthreads();
#pragma unroll
    for (int s = 0; s < 32; s += 8)
        Wt[(size_t)(bx * 32 + ly + s) * K + by * 32 + lx] = f2bf(t[lx][ly + s]);
}

// ---------------- bf16 MFMA GEMM: Cb[M,NC] = opt_relu(A[M,K] @ Bt[NC,K]^T + bias) ----------------
// 128x128 tile, BK=32, 4 waves (2x2), each wave 64x64 = 4x4 frags of 16x16x32.
// LDS tiles [128][32] bf16, seg-swizzled: LDS slot c holds global seg c ^ ((row>>1)&3).

__global__ __launch_bounds__(256) void k_gemm_bf16(const ushort* __restrict__ A, const ushort* __restrict__ Bt,
                                                   const float* __restrict__ bias, ushort* __restrict__ Cb,
                                                   int relu, int M, int K, int NC) {
    __shared__ short As[4096];  // 128 rows x 32 bf16
    __shared__ short Bs[4096];
    int tid = threadIdx.x;
    int lane = tid & 63, w = tid >> 6;
    int wr = w >> 1, wc = w & 1;
    int row0 = blockIdx.x * 128, col0 = blockIdx.y * 128;

    f32x4 acc[4][4] = {};

    int r15 = lane & 15;
    int swz = ((r15 >> 1) & 3) << 3;           // read-side XOR, in shorts
    int kseg = (lane >> 4) << 3;               // k seg this lane needs (8 bf16)
    int koff = kseg ^ swz;

    // staging geometry (same for A and B tiles)
    int st_row[2], st_cg[2];
#pragma unroll
    for (int i = 0; i < 2; ++i) {
        int row = i * 64 + (tid >> 2);
        st_row[i] = row;
        st_cg[i] = (tid & 3) ^ ((row >> 1) & 3);
    }

    for (int k0 = 0; k0 < K; k0 += 32) {
#pragma unroll
        for (int i = 0; i < 2; ++i) {
            int ra = row0 + st_row[i];
            if (ra > M - 1) ra = M - 1;
            gll16(A + (size_t)ra * K + k0 + st_cg[i] * 8, &As[i * 2048 + w * 512]);
            gll16(Bt + (size_t)(col0 + st_row[i]) * K + k0 + st_cg[i] * 8, &Bs[i * 2048 + w * 512]);
        }
        __syncthreads();
        bf16x8 af[4], bfr[4];
#pragma unroll
        for (int m = 0; m < 4; ++m) af[m] = *(const bf16x8*)&As[(wr * 64 + m * 16 + r15) * 32 + koff];
#pragma unroll
        for (int n = 0; n < 4; ++n) bfr[n] = *(const bf16x8*)&Bs[(wc * 64 + n * 16 + r15) * 32 + koff];
#pragma unroll
        for (int m = 0; m < 4; ++m)
#pragma unroll
            for (int n = 0; n < 4; ++n)
                acc[m][n] = __builtin_amdgcn_mfma_f32_16x16x32_bf16(af[m], bfr[n], acc[m][n], 0, 0, 0);
        __syncthreads();
    }

    // epilogue: C/D layout col = lane&15, row = (lane>>4)*4 + r
    int cc = lane & 15, rq = (lane >> 4) * 4;
#pragma unroll
    for (int m = 0; m < 4; ++m) {
#pragma unroll
        for (int r = 0; r < 4; ++r) {
            int gr = row0 + wr * 64 + m * 16 + rq + r;
            if (gr >= M) continue;
#pragma unroll
            for (int n = 0; n < 4; ++n) {
                int gc = col0 + wc * 64 + n * 16 + cc;
                float v = acc[m][n][r];
                if (bias) v += bias[gc];
                if (relu) v = fmaxf(v, 0.f);
                Cb[(size_t)gr * NC + gc] = f2bf(v);
            }
        }
    }
}

// ---------------- aggregation (bf16 -> bf16): aout[n] = dinv[n] * sum dinv[s]*hin[s] ----------------
// one wave per node; lane covers 4 bf16 cols (8B); per-wave row gather = 512B contiguous

__global__ __launch_bounds__(256) void k_aggregate_bf(const ushort* __restrict__ hin, const int* __restrict__ rowp,
                                                      const int* __restrict__ csrc, const float* __restrict__ dinv,
                                                      ushort* __restrict__ aout, int n) {
    int wave = threadIdx.x >> 6, lane = threadIdx.x & 63;
    int node = blockIdx.x * 4 + wave;
    if (node >= n) return;
    int beg = rowp[node], end = rowp[node + 1];
    int c = lane * 4;
    float4 acc = make_float4(0.f, 0.f, 0.f, 0.f);
    for (int i = beg; i < end; ++i) {
        int s = csrc[i];
        float w = dinv[s];
        ushort4 r = *(const ushort4*)&hin[(size_t)s * HID + c];
        acc.x += w * bf2f(r.x); acc.y += w * bf2f(r.y);
        acc.z += w * bf2f(r.z); acc.w += w * bf2f(r.w);
    }
    float dn = dinv[node];
    ushort4 o;
    o.x = f2bf(dn * acc.x); o.y = f2bf(dn * acc.y);
    o.z = f2bf(dn * acc.z); o.w = f2bf(dn * acc.w);
    *(ushort4*)&aout[(size_t)node * HID + c] = o;
}

// ---------------- fused pool + projection + LayerNorm (one block per graph) ----------------

__global__ __launch_bounds__(256) void k_pool_proj_ln(const ushort* __restrict__ hbf, const int* __restrict__ gstart,
                                                      const float* __restrict__ Wp, const float* __restrict__ bp,
                                                      const float* __restrict__ gamma, const float* __restrict__ beta,
                                                      float* __restrict__ out) {
    __shared__ float mol[HID];
    __shared__ float part[4][NODE_DIM];
    int g = blockIdx.x;
    int t = threadIdx.x;
    int beg = gstart[g], end = gstart[g + 1];
    float sum = 0.f;
    for (int r = beg; r < end; ++r) sum += bf2f(hbf[(size_t)r * HID + t]);
    float inv = 1.0f / fmaxf((float)(end - beg), 1.0f);
    mol[t] = sum * inv;
    __syncthreads();
    int w = t >> 6, j = t & 63;
    float p = 0.f;
    int k0 = w * 64;
#pragma unroll 8
    for (int k = 0; k < 64; ++k) p += mol[k0 + k] * Wp[(size_t)(k0 + k) * NODE_DIM + j];
    part[w][j] = p;
    __syncthreads();
    if (t < 64) {
        float pj = part[0][j] + part[1][j] + part[2][j] + part[3][j] + bp[j];
        float s = pj;
#pragma unroll
        for (int m = 1; m < 64; m <<= 1) s += __shfl_xor(s, m);
        float mu = s * (1.0f / 64.0f);
        float d = pj - mu;
        float vs = d * d;
#pragma unroll
        for (int m = 1; m < 64; m <<= 1) vs += __shfl_xor(vs, m);
        out[(size_t)g * NODE_DIM + j] = d * rsqrtf(vs * (1.0f / 64.0f) + LN_EPS) * gamma[j] + beta[j];
    }
}

// ---------------- launch ----------------

extern "C" void kernel_launch(void* const* d_in, const int* in_sizes, int n_in,
                              void* d_out, int out_size, void* d_ws, size_t ws_size,
                              hipStream_t stream) {
    const float* x     = (const float*)d_in[0];
    const int*   ei    = (const int*)d_in[1];
    const int*   batch = (const int*)d_in[2];
    const float* W_enc = (const float*)d_in[3];
    const float* b_enc = (const float*)d_in[4];
    const float* Ws    = (const float*)d_in[5];
    const float* bs    = (const float*)d_in[6];
    const float* Wp    = (const float*)d_in[7];
    const float* bp    = (const float*)d_in[8];
    const float* gamma = (const float*)d_in[9];
    const float* beta  = (const float*)d_in[10];
    float* out = (float*)d_out;

    // workspace layout (all bf16 activations)
    ushort* hbf  = (ushort*)d_ws;                      // N*HID bf16
    ushort* abf  = hbf + (size_t)NN * HID;             // N*HID bf16 (aggregated)
    ushort* xbf  = abf + (size_t)NN * HID;             // N*ATOM_DIM bf16
    ushort* wtE  = xbf + (size_t)NN * ATOM_DIM;        // 256*128 (W_enc^T)
    ushort* wtL  = wtE + HID * ATOM_DIM;               // 3 * 256*256 (Ws^T)
    float*  dinv = (float*)(wtL + (size_t)NUM_LAYERS * HID * HID);  // N
    int* cnt    = (int*)(dinv + NN);                   // N
    int* rowp   = cnt + NN;                            // N+1
    int* fill   = rowp + NN + 1;                       // N
    int* csrc   = fill + NN;                           // E+N
    int* csum   = csrc + (EE + NN);                    // 64
    int* gstart = csum + 64;                           // G+1

    const int EN = EE + NN;
    const int NCH = (NN + 1023) / 1024;

    // input conversions
    k_cvt<<<(NN * ATOM_DIM / 4 + 255) / 256, 256, 0, stream>>>(x, xbf, NN * ATOM_DIM);
    {
        dim3 gE(HID / 32, ATOM_DIM / 32);
        k_wt<<<gE, 256, 0, stream>>>(W_enc, wtE, ATOM_DIM, HID);
        dim3 gL(HID / 32, HID / 32);
        for (int l = 0; l < NUM_LAYERS; ++l)
            k_wt<<<gL, 256, 0, stream>>>(Ws + (size_t)l * HID * HID, wtL + (size_t)l * HID * HID, HID, HID);
    }

    // CSR build + graph boundaries
    k_init_cnt<<<(NN + 255) / 256, 256, 0, stream>>>(cnt, NN);
    k_count<<<(EE + 255) / 256, 256, 0, stream>>>(ei, cnt, EE);
    k_scan1<<<NCH, 256, 0, stream>>>(cnt, rowp, csum, NN);
    k_scan2<<<NCH, 256, 0, stream>>>(rowp, fill, csum, NN);
    k_dinv<<<(NN + 255) / 256, 256, 0, stream>>>(cnt, dinv, NN);
    k_fill<<<(EN + 255) / 256, 256, 0, stream>>>(ei, fill, csrc, EE, NN);
    k_gbound<<<(GG + 1 + 255) / 256, 256, 0, stream>>>(batch, gstart, NN, GG);

    dim3 ggrid((NN + 127) / 128, HID / 128);

    // atom encoder: hbf = bf16(x @ W_enc + b_enc)   (no relu)
    k_gemm_bf16<<<ggrid, 256, 0, stream>>>(xbf, wtE, b_enc, hbf, 0, NN, ATOM_DIM, HID);

    // GCN layers, reordered: agg(h) @ W  ==  agg(h @ W)
    for (int l = 0; l < NUM_LAYERS; ++l) {
        k_aggregate_bf<<<(NN + 3) / 4, 256, 0, stream>>>(hbf, rowp, csrc, dinv, abf, NN);
        k_gemm_bf16<<<ggrid, 256, 0, stream>>>(abf, wtL + (size_t)l * HID * HID, bs + (size_t)l * HID, hbf, 1, NN, HID, HID);
    }

    // fused global-mean-pool + projection + LayerNorm
    k_pool_proj_ln<<<GG, 256, 0, stream>>>(hbf, gstart, Wp, bp, gamma, beta, out);
}

// Round 5
// 312.159 us; speedup vs baseline: 2.5571x; 1.1560x over previous
//
#include <hip/hip_runtime.h>
#include <hip/hip_bf16.h>

#define NN 50000
#define EE 300000
#define ATOM_DIM 128
#define HID 256
#define NODE_DIM 64
#define NUM_LAYERS 3
#define GG 2000
#define LN_EPS 1e-5f

typedef __attribute__((ext_vector_type(8))) short bf16x8;
typedef __attribute__((ext_vector_type(4))) float f32x4;

__device__ __forceinline__ ushort f2bf(float f) {
    __hip_bfloat16 h = __float2bfloat16(f);
    return *reinterpret_cast<ushort*>(&h);
}
__device__ __forceinline__ float bf2f(ushort u) {
    __hip_bfloat16 h = *reinterpret_cast<__hip_bfloat16*>(&u);
    return __bfloat162float(h);
}

__device__ __forceinline__ void gll16(const void* g, void* l) {
    __builtin_amdgcn_global_load_lds((const __attribute__((address_space(1))) unsigned int*)g,
                                     (__attribute__((address_space(3))) unsigned int*)l, 16, 0, 0);
}

// ---------------- CSR build ----------------
// cnt[] = #in-edges (real edges only; self-loop accounted as +1 downstream)

__global__ __launch_bounds__(256) void k_count(const int* __restrict__ ei, int* cnt, int e_total) {
    int e = blockIdx.x * 256 + threadIdx.x;
    if (e < e_total) atomicAdd(&cnt[ei[e_total + e]], 1);  // dst = ei[1][e]
}

// exclusive scan over (cnt[i]+1); chunk = 1024 per block
__global__ __launch_bounds__(256) void k_scan1(const int* __restrict__ cnt, int* __restrict__ rowp,
                                               int* __restrict__ csum, int n) {
    __shared__ int s[256];
    int tid = threadIdx.x;
    int base = blockIdx.x * 1024 + tid * 4;
    int v[4];
#pragma unroll
    for (int j = 0; j < 4; ++j) { int i = base + j; v[j] = (i < n) ? cnt[i] + 1 : 0; }
    int tsum = v[0] + v[1] + v[2] + v[3];
    s[tid] = tsum;
    __syncthreads();
    for (int off = 1; off < 256; off <<= 1) {
        int t = (tid >= off) ? s[tid - off] : 0;
        __syncthreads();
        s[tid] += t;
        __syncthreads();
    }
    int excl = s[tid] - tsum;
#pragma unroll
    for (int j = 0; j < 4; ++j) { int i = base + j; if (i < n) rowp[i] = excl; excl += v[j]; }
    if (tid == 255) csum[blockIdx.x] = s[255];
}

// finalize scan; also emit fill[] (CSR cursor) and dinv[] = rsqrt(deg)
__global__ __launch_bounds__(256) void k_scan2(int* __restrict__ rowp, int* __restrict__ fill,
                                               const int* __restrict__ csum, const int* __restrict__ cnt,
                                               float* __restrict__ dinv, int n) {
    __shared__ int soff;
    int chunk = blockIdx.x;
    if (threadIdx.x == 0) {
        int o = 0;
        for (int c = 0; c < chunk; ++c) o += csum[c];
        soff = o;
    }
    __syncthreads();
    int off = soff;
    int base = chunk * 1024 + threadIdx.x * 4;
#pragma unroll
    for (int j = 0; j < 4; ++j) {
        int i = base + j;
        if (i < n) {
            int r = rowp[i] + off;
            rowp[i] = r; fill[i] = r;
            dinv[i] = rsqrtf((float)(cnt[i] + 1));
        }
    }
    if (chunk == gridDim.x - 1 && threadIdx.x == 255) rowp[n] = off + csum[chunk];
}

__global__ __launch_bounds__(256) void k_fill(const int* __restrict__ ei, int* fill, int* __restrict__ csrc,
                                              int e_total, int n) {
    int e = blockIdx.x * 256 + threadIdx.x;
    int tot = e_total + n;
    if (e >= tot) return;
    int s, d;
    if (e < e_total) { s = ei[e]; d = ei[e_total + e]; }
    else { s = d = e - e_total; }
    int pos = atomicAdd(&fill[d], 1);
    csrc[pos] = s;
}

__global__ __launch_bounds__(256) void k_gbound(const int* __restrict__ batch, int* __restrict__ gstart,
                                                int n, int g_total) {
    int g = blockIdx.x * 256 + threadIdx.x;
    if (g > g_total) return;
    int lo = 0, hi = n;
    while (lo < hi) { int mid = (lo + hi) >> 1; if (batch[mid] < g) lo = mid + 1; else hi = mid; }
    gstart[g] = lo;
}

// ---------------- fp32 -> bf16 convert ----------------

__global__ __launch_bounds__(256) void k_cvt(const float* __restrict__ in, ushort* __restrict__ out, int n) {
    int i = (blockIdx.x * 256 + threadIdx.x) * 4;
    if (i >= n) return;
    float4 v = *(const float4*)&in[i];
    ushort4 o;
    o.x = f2bf(v.x); o.y = f2bf(v.y); o.z = f2bf(v.z); o.w = f2bf(v.w);
    *(ushort4*)&out[i] = o;
}

// ---------------- weight transpose + convert: Wt[n][k] = bf16(W[k][n]); z = layer ----------------

__global__ __launch_bounds__(256) void k_wt(const float* __restrict__ W, ushort* __restrict__ Wt, int K, int N) {
    __shared__ float t[32][33];
    size_t lo = (size_t)blockIdx.z * K * N;
    const float* Wz = W + lo;
    ushort* Wtz = Wt + lo;
    int bx = blockIdx.x;  // along N
    int by = blockIdx.y;  // along K
    int lx = threadIdx.x & 31, ly = threadIdx.x >> 5;  // 32x8
#pragma unroll
    for (int s = 0; s < 32; s += 8)
        t[ly + s][lx] = Wz[(size_t)(by * 32 + ly + s) * N + bx * 32 + lx];
    __syncthreads();
#pragma unroll
    for (int s = 0; s < 32; s += 8)
        Wtz[(size_t)(bx * 32 + ly + s) * K + by * 32 + lx] = f2bf(t[lx][ly + s]);
}

// ---------------- bf16 MFMA GEMM: Cb[M,NC] = opt_relu(A[M,K] @ Bt[NC,K]^T + bias) ----------------

__global__ __launch_bounds__(256) void k_gemm_bf16(const ushort* __restrict__ A, const ushort* __restrict__ Bt,
                                                   const float* __restrict__ bias, ushort* __restrict__ Cb,
                                                   int relu, int M, int K, int NC) {
    __shared__ short As[4096];  // 128 rows x 32 bf16
    __shared__ short Bs[4096];
    int tid = threadIdx.x;
    int lane = tid & 63, w = tid >> 6;
    int wr = w >> 1, wc = w & 1;
    int row0 = blockIdx.x * 128, col0 = blockIdx.y * 128;

    f32x4 acc[4][4] = {};

    int r15 = lane & 15;
    int swz = ((r15 >> 1) & 3) << 3;
    int kseg = (lane >> 4) << 3;
    int koff = kseg ^ swz;

    int st_row[2], st_cg[2];
#pragma unroll
    for (int i = 0; i < 2; ++i) {
        int row = i * 64 + (tid >> 2);
        st_row[i] = row;
        st_cg[i] = (tid & 3) ^ ((row >> 1) & 3);
    }

    for (int k0 = 0; k0 < K; k0 += 32) {
#pragma unroll
        for (int i = 0; i < 2; ++i) {
            int ra = row0 + st_row[i];
            if (ra > M - 1) ra = M - 1;
            gll16(A + (size_t)ra * K + k0 + st_cg[i] * 8, &As[i * 2048 + w * 512]);
            gll16(Bt + (size_t)(col0 + st_row[i]) * K + k0 + st_cg[i] * 8, &Bs[i * 2048 + w * 512]);
        }
        __syncthreads();
        bf16x8 af[4], bfr[4];
#pragma unroll
        for (int m = 0; m < 4; ++m) af[m] = *(const bf16x8*)&As[(wr * 64 + m * 16 + r15) * 32 + koff];
#pragma unroll
        for (int n = 0; n < 4; ++n) bfr[n] = *(const bf16x8*)&Bs[(wc * 64 + n * 16 + r15) * 32 + koff];
#pragma unroll
        for (int m = 0; m < 4; ++m)
#pragma unroll
            for (int n = 0; n < 4; ++n)
                acc[m][n] = __builtin_amdgcn_mfma_f32_16x16x32_bf16(af[m], bfr[n], acc[m][n], 0, 0, 0);
        __syncthreads();
    }

    int cc = lane & 15, rq = (lane >> 4) * 4;
#pragma unroll
    for (int m = 0; m < 4; ++m) {
#pragma unroll
        for (int r = 0; r < 4; ++r) {
            int gr = row0 + wr * 64 + m * 16 + rq + r;
            if (gr >= M) continue;
#pragma unroll
            for (int n = 0; n < 4; ++n) {
                int gc = col0 + wc * 64 + n * 16 + cc;
                float v = acc[m][n][r];
                if (bias) v += bias[gc];
                if (relu) v = fmaxf(v, 0.f);
                Cb[(size_t)gr * NC + gc] = f2bf(v);
            }
        }
    }
}

// ---------------- aggregation (bf16 -> bf16): aout[n] = dinv[n] * sum dinv[s]*hin[s] ----------------
// one wave per node. Lane-cooperative index prefetch (csrc + dinv in 2 vector loads),
// then 4 independent 512B row-gathers in flight per inner step.

__global__ __launch_bounds__(256) void k_aggregate_bf(const ushort* __restrict__ hin, const int* __restrict__ rowp,
                                                      const int* __restrict__ csrc, const float* __restrict__ dinv,
                                                      ushort* __restrict__ aout, int n) {
    int wave = threadIdx.x >> 6, lane = threadIdx.x & 63;
    int node = blockIdx.x * 4 + wave;
    if (node >= n) return;
    int beg = rowp[node], end = rowp[node + 1];
    const ushort* hc = hin + lane * 4;
    float4 acc = make_float4(0.f, 0.f, 0.f, 0.f);
    for (int c0 = beg; c0 < end; c0 += 64) {
        int m = end - c0; if (m > 64) m = 64;
        int idx = (lane < m) ? csrc[c0 + lane] : 0;
        float dv = (lane < m) ? dinv[idx] : 0.f;
        int j = 0;
        for (; j + 4 <= m; j += 4) {
            int s0 = __shfl(idx, j), s1 = __shfl(idx, j + 1), s2 = __shfl(idx, j + 2), s3 = __shfl(idx, j + 3);
            float w0 = __shfl(dv, j), w1 = __shfl(dv, j + 1), w2 = __shfl(dv, j + 2), w3 = __shfl(dv, j + 3);
            ushort4 r0 = *(const ushort4*)&hc[(size_t)s0 * HID];
            ushort4 r1 = *(const ushort4*)&hc[(size_t)s1 * HID];
            ushort4 r2 = *(const ushort4*)&hc[(size_t)s2 * HID];
            ushort4 r3 = *(const ushort4*)&hc[(size_t)s3 * HID];
            acc.x += w0 * bf2f(r0.x) + w1 * bf2f(r1.x) + w2 * bf2f(r2.x) + w3 * bf2f(r3.x);
            acc.y += w0 * bf2f(r0.y) + w1 * bf2f(r1.y) + w2 * bf2f(r2.y) + w3 * bf2f(r3.y);
            acc.z += w0 * bf2f(r0.z) + w1 * bf2f(r1.z) + w2 * bf2f(r2.z) + w3 * bf2f(r3.z);
            acc.w += w0 * bf2f(r0.w) + w1 * bf2f(r1.w) + w2 * bf2f(r2.w) + w3 * bf2f(r3.w);
        }
        for (; j < m; ++j) {
            int s = __shfl(idx, j);
            float wj = __shfl(dv, j);
            ushort4 r = *(const ushort4*)&hc[(size_t)s * HID];
            acc.x += wj * bf2f(r.x); acc.y += wj * bf2f(r.y);
            acc.z += wj * bf2f(r.z); acc.w += wj * bf2f(r.w);
        }
    }
    float dn = dinv[node];
    ushort4 o;
    o.x = f2bf(dn * acc.x); o.y = f2bf(dn * acc.y);
    o.z = f2bf(dn * acc.z); o.w = f2bf(dn * acc.w);
    *(ushort4*)&aout[(size_t)node * HID + lane * 4] = o;
}

// ---------------- fused pool + projection + LayerNorm (one block per graph) ----------------

__global__ __launch_bounds__(256) void k_pool_proj_ln(const ushort* __restrict__ hbf, const int* __restrict__ gstart,
                                                      const float* __restrict__ Wp, const float* __restrict__ bp,
                                                      const float* __restrict__ gamma, const float* __restrict__ beta,
                                                      float* __restrict__ out) {
    __shared__ float mol[HID];
    __shared__ float part[4][NODE_DIM];
    int g = blockIdx.x;
    int t = threadIdx.x;
    int beg = gstart[g], end = gstart[g + 1];
    float sum = 0.f;
    for (int r = beg; r < end; ++r) sum += bf2f(hbf[(size_t)r * HID + t]);
    float inv = 1.0f / fmaxf((float)(end - beg), 1.0f);
    mol[t] = sum * inv;
    __syncthreads();
    int w = t >> 6, j = t & 63;
    float p = 0.f;
    int k0 = w * 64;
#pragma unroll 8
    for (int k = 0; k < 64; ++k) p += mol[k0 + k] * Wp[(size_t)(k0 + k) * NODE_DIM + j];
    part[w][j] = p;
    __syncthreads();
    if (t < 64) {
        float pj = part[0][j] + part[1][j] + part[2][j] + part[3][j] + bp[j];
        float s = pj;
#pragma unroll
        for (int m = 1; m < 64; m <<= 1) s += __shfl_xor(s, m);
        float mu = s * (1.0f / 64.0f);
        float d = pj - mu;
        float vs = d * d;
#pragma unroll
        for (int m = 1; m < 64; m <<= 1) vs += __shfl_xor(vs, m);
        out[(size_t)g * NODE_DIM + j] = d * rsqrtf(vs * (1.0f / 64.0f) + LN_EPS) * gamma[j] + beta[j];
    }
}

// ---------------- launch ----------------

extern "C" void kernel_launch(void* const* d_in, const int* in_sizes, int n_in,
                              void* d_out, int out_size, void* d_ws, size_t ws_size,
                              hipStream_t stream) {
    const float* x     = (const float*)d_in[0];
    const int*   ei    = (const int*)d_in[1];
    const int*   batch = (const int*)d_in[2];
    const float* W_enc = (const float*)d_in[3];
    const float* b_enc = (const float*)d_in[4];
    const float* Ws    = (const float*)d_in[5];
    const float* bs    = (const float*)d_in[6];
    const float* Wp    = (const float*)d_in[7];
    const float* bp    = (const float*)d_in[8];
    const float* gamma = (const float*)d_in[9];
    const float* beta  = (const float*)d_in[10];
    float* out = (float*)d_out;

    // workspace layout (all bf16 activations)
    ushort* hbf  = (ushort*)d_ws;                      // N*HID bf16
    ushort* abf  = hbf + (size_t)NN * HID;             // N*HID bf16 (aggregated)
    ushort* xbf  = abf + (size_t)NN * HID;             // N*ATOM_DIM bf16
    ushort* wtE  = xbf + (size_t)NN * ATOM_DIM;        // 256*128 (W_enc^T)
    ushort* wtL  = wtE + HID * ATOM_DIM;               // 3 * 256*256 (Ws^T)
    float*  dinv = (float*)(wtL + (size_t)NUM_LAYERS * HID * HID);  // N
    int* cnt    = (int*)(dinv + NN);                   // N
    int* rowp   = cnt + NN;                            // N+1
    int* fill   = rowp + NN + 1;                       // N
    int* csrc   = fill + NN;                           // E+N
    int* csum   = csrc + (EE + NN);                    // 64
    int* gstart = csum + 64;                           // G+1

    const int EN = EE + NN;
    const int NCH = (NN + 1023) / 1024;

    // input conversions
    k_cvt<<<(NN * ATOM_DIM / 4 + 255) / 256, 256, 0, stream>>>(x, xbf, NN * ATOM_DIM);
    {
        dim3 gE(HID / 32, ATOM_DIM / 32, 1);
        k_wt<<<gE, 256, 0, stream>>>(W_enc, wtE, ATOM_DIM, HID);
        dim3 gL(HID / 32, HID / 32, NUM_LAYERS);
        k_wt<<<gL, 256, 0, stream>>>(Ws, wtL, HID, HID);
    }

    // CSR build + graph boundaries
    hipMemsetAsync(cnt, 0, NN * sizeof(int), stream);
    k_count<<<(EE + 255) / 256, 256, 0, stream>>>(ei, cnt, EE);
    k_scan1<<<NCH, 256, 0, stream>>>(cnt, rowp, csum, NN);
    k_scan2<<<NCH, 256, 0, stream>>>(rowp, fill, csum, cnt, dinv, NN);
    k_fill<<<(EN + 255) / 256, 256, 0, stream>>>(ei, fill, csrc, EE, NN);
    k_gbound<<<(GG + 1 + 255) / 256, 256, 0, stream>>>(batch, gstart, NN, GG);

    dim3 ggrid((NN + 127) / 128, HID / 128);

    // atom encoder: hbf = bf16(x @ W_enc + b_enc)   (no relu)
    k_gemm_bf16<<<ggrid, 256, 0, stream>>>(xbf, wtE, b_enc, hbf, 0, NN, ATOM_DIM, HID);

    // GCN layers, reordered: agg(h) @ W  ==  agg(h @ W)
    for (int l = 0; l < NUM_LAYERS; ++l) {
        k_aggregate_bf<<<(NN + 3) / 4, 256, 0, stream>>>(hbf, rowp, csrc, dinv, abf, NN);
        k_gemm_bf16<<<ggrid, 256, 0, stream>>>(abf, wtL + (size_t)l * HID * HID, bs + (size_t)l * HID, hbf, 1, NN, HID, HID);
    }

    // fused global-mean-pool + projection + LayerNorm
    k_pool_proj_ln<<<GG, 256, 0, stream>>>(hbf, gstart, Wp, bp, gamma, beta, out);
}

// Round 6
// 305.196 us; speedup vs baseline: 2.6154x; 1.0228x over previous
//
#include <hip/hip_runtime.h>
#include <hip/hip_bf16.h>

#define NN 50000
#define EE 300000
#define ATOM_DIM 128
#define HID 256
#define NODE_DIM 64
#define NUM_LAYERS 3
#define GG 2000
#define LN_EPS 1e-5f
#define CSRC_CAP 704512   // >= E + 8*N (padded-to-8 bound = 700000)

typedef __attribute__((ext_vector_type(8))) short bf16x8;
typedef __attribute__((ext_vector_type(4))) float f32x4;

__device__ __forceinline__ ushort f2bf(float f) {
    __hip_bfloat16 h = __float2bfloat16(f);
    return *reinterpret_cast<ushort*>(&h);
}
__device__ __forceinline__ float bf2f(ushort u) {
    __hip_bfloat16 h = *reinterpret_cast<__hip_bfloat16*>(&u);
    return __bfloat162float(h);
}

__device__ __forceinline__ void gll16(const void* g, void* l) {
    __builtin_amdgcn_global_load_lds((const __attribute__((address_space(1))) unsigned int*)g,
                                     (__attribute__((address_space(3))) unsigned int*)l, 16, 0, 0);
}

// ---------------- fused prep kernel: branch ladder over flat grid ----------------
// segments: [cvt x][wt enc][wt layers][gbound][csrc prefill][cnt zero][hbf zero-row]

#define PB_CVT   6250   // 1.6M float4 (N*ATOM/4)
#define PB_WTE   32     // (256/32)*(128/32)
#define PB_WTL   192    // 64 * 3 layers
#define PB_GB    8      // 2001 threads
#define PB_CSRC  688    // 176128 int4
#define PB_CNT   49     // 12500 int4
#define PB_ZROW  1
#define PB_TOTAL (PB_CVT + PB_WTE + PB_WTL + PB_GB + PB_CSRC + PB_CNT + PB_ZROW)

__device__ __forceinline__ void wt_tile(const float* __restrict__ W, ushort* __restrict__ Wt,
                                        int K, int N, int bx, int by) {
    __shared__ float t[32][33];
    int lx = threadIdx.x & 31, ly = threadIdx.x >> 5;  // 32x8
#pragma unroll
    for (int s = 0; s < 32; s += 8)
        t[ly + s][lx] = W[(size_t)(by * 32 + ly + s) * N + bx * 32 + lx];
    __syncthreads();
#pragma unroll
    for (int s = 0; s < 32; s += 8)
        Wt[(size_t)(bx * 32 + ly + s) * K + by * 32 + lx] = f2bf(t[lx][ly + s]);
}

__global__ __launch_bounds__(256) void k_prep(const float* __restrict__ x, ushort* __restrict__ xbf,
                                              const float* __restrict__ W_enc, ushort* __restrict__ wtE,
                                              const float* __restrict__ Ws, ushort* __restrict__ wtL,
                                              const int* __restrict__ batch, int* __restrict__ gstart,
                                              int* __restrict__ cnt, int* __restrict__ csrc,
                                              ushort* __restrict__ hbf_zero_row) {
    int b = blockIdx.x;
    int tid = threadIdx.x;
    if (b < PB_CVT) {
        int i = (b * 256 + tid) * 4;
        float4 v = *(const float4*)&x[i];
        ushort4 o;
        o.x = f2bf(v.x); o.y = f2bf(v.y); o.z = f2bf(v.z); o.w = f2bf(v.w);
        *(ushort4*)&xbf[i] = o;
        return;
    }
    b -= PB_CVT;
    if (b < PB_WTE) {  // W_enc^T: K=128, N=256
        wt_tile(W_enc, wtE, ATOM_DIM, HID, b & 7, b >> 3);
        return;
    }
    b -= PB_WTE;
    if (b < PB_WTL) {  // Ws^T: 3 layers of 256x256
        int z = b >> 6, r = b & 63;
        wt_tile(Ws + (size_t)z * HID * HID, wtL + (size_t)z * HID * HID, HID, HID, r & 7, r >> 3);
        return;
    }
    b -= PB_WTL;
    if (b < PB_GB) {   // graph boundaries: lower_bound over sorted batch
        int g = b * 256 + tid;
        if (g > GG) return;
        int lo = 0, hi = NN;
        while (lo < hi) { int mid = (lo + hi) >> 1; if (batch[mid] < g) lo = mid + 1; else hi = mid; }
        gstart[g] = lo;
        return;
    }
    b -= PB_GB;
    if (b < PB_CSRC) { // prefill csrc with zero-row index NN
        int i = (b * 256 + tid) * 4;
        if (i < CSRC_CAP) *(int4*)&csrc[i] = make_int4(NN, NN, NN, NN);
        return;
    }
    b -= PB_CSRC;
    if (b < PB_CNT) {  // zero cnt
        int i = (b * 256 + tid) * 4;
        if (i < NN) *(int4*)&cnt[i] = make_int4(0, 0, 0, 0);
        return;
    }
    // zero row of hbf (row index NN)
    hbf_zero_row[tid] = 0;
}

// ---------------- CSR build ----------------

__global__ __launch_bounds__(256) void k_count(const int* __restrict__ ei, int* cnt, int e_total) {
    int e = blockIdx.x * 256 + threadIdx.x;
    if (e < e_total) atomicAdd(&cnt[ei[e_total + e]], 1);  // dst = ei[1][e]
}

// exclusive scan over padded counts ((cnt+1+7)&~7); chunk = 1024 per block
__global__ __launch_bounds__(256) void k_scan1(const int* __restrict__ cnt, int* __restrict__ rowp,
                                               int* __restrict__ csum, int n) {
    __shared__ int s[256];
    int tid = threadIdx.x;
    int base = blockIdx.x * 1024 + tid * 4;
    int v[4];
#pragma unroll
    for (int j = 0; j < 4; ++j) { int i = base + j; v[j] = (i < n) ? ((cnt[i] + 8) & ~7) : 0; }
    int tsum = v[0] + v[1] + v[2] + v[3];
    s[tid] = tsum;
    __syncthreads();
    for (int off = 1; off < 256; off <<= 1) {
        int t = (tid >= off) ? s[tid - off] : 0;
        __syncthreads();
        s[tid] += t;
        __syncthreads();
    }
    int excl = s[tid] - tsum;
#pragma unroll
    for (int j = 0; j < 4; ++j) { int i = base + j; if (i < n) rowp[i] = excl; excl += v[j]; }
    if (tid == 255) csum[blockIdx.x] = s[255];
}

// finalize scan; emit fill[] cursor and dinv[] = rsqrt(real degree)
__global__ __launch_bounds__(256) void k_scan2(int* __restrict__ rowp, int* __restrict__ fill,
                                               const int* __restrict__ csum, const int* __restrict__ cnt,
                                               float* __restrict__ dinv, int n) {
    __shared__ int soff;
    int chunk = blockIdx.x;
    if (threadIdx.x == 0) {
        int o = 0;
        for (int c = 0; c < chunk; ++c) o += csum[c];
        soff = o;
    }
    __syncthreads();
    int off = soff;
    int base = chunk * 1024 + threadIdx.x * 4;
#pragma unroll
    for (int j = 0; j < 4; ++j) {
        int i = base + j;
        if (i < n) {
            int r = rowp[i] + off;
            rowp[i] = r; fill[i] = r;
            dinv[i] = rsqrtf((float)(cnt[i] + 1));
        }
    }
    if (chunk == gridDim.x - 1 && threadIdx.x == 255) rowp[n] = off + csum[chunk];
}

__global__ __launch_bounds__(256) void k_fill(const int* __restrict__ ei, int* fill, int* __restrict__ csrc,
                                              int e_total, int n) {
    int e = blockIdx.x * 256 + threadIdx.x;
    int tot = e_total + n;
    if (e >= tot) return;
    int s, d;
    if (e < e_total) { s = ei[e]; d = ei[e_total + e]; }
    else { s = d = e - e_total; }
    int pos = atomicAdd(&fill[d], 1);
    csrc[pos] = s;
}

// ---------------- bf16 MFMA GEMM: Cb = opt_dscale( opt_relu(A @ Bt^T + bias) ) ----------------
// 128x128 tile, BK=32, 4 waves (2x2), each wave 64x64 = 4x4 frags of 16x16x32.

__global__ __launch_bounds__(256) void k_gemm_bf16(const ushort* __restrict__ A, const ushort* __restrict__ Bt,
                                                   const float* __restrict__ bias, ushort* __restrict__ Cb,
                                                   const float* __restrict__ dscale, int relu,
                                                   int M, int K, int NC) {
    __shared__ short As[4096];  // 128 rows x 32 bf16
    __shared__ short Bs[4096];
    int tid = threadIdx.x;
    int lane = tid & 63, w = tid >> 6;
    int wr = w >> 1, wc = w & 1;
    int row0 = blockIdx.x * 128, col0 = blockIdx.y * 128;

    f32x4 acc[4][4] = {};

    int r15 = lane & 15;
    int swz = ((r15 >> 1) & 3) << 3;
    int kseg = (lane >> 4) << 3;
    int koff = kseg ^ swz;

    int st_row[2], st_cg[2];
#pragma unroll
    for (int i = 0; i < 2; ++i) {
        int row = i * 64 + (tid >> 2);
        st_row[i] = row;
        st_cg[i] = (tid & 3) ^ ((row >> 1) & 3);
    }

    for (int k0 = 0; k0 < K; k0 += 32) {
#pragma unroll
        for (int i = 0; i < 2; ++i) {
            int ra = row0 + st_row[i];
            if (ra > M - 1) ra = M - 1;
            gll16(A + (size_t)ra * K + k0 + st_cg[i] * 8, &As[i * 2048 + w * 512]);
            gll16(Bt + (size_t)(col0 + st_row[i]) * K + k0 + st_cg[i] * 8, &Bs[i * 2048 + w * 512]);
        }
        __syncthreads();
        bf16x8 af[4], bfr[4];
#pragma unroll
        for (int m = 0; m < 4; ++m) af[m] = *(const bf16x8*)&As[(wr * 64 + m * 16 + r15) * 32 + koff];
#pragma unroll
        for (int n = 0; n < 4; ++n) bfr[n] = *(const bf16x8*)&Bs[(wc * 64 + n * 16 + r15) * 32 + koff];
#pragma unroll
        for (int m = 0; m < 4; ++m)
#pragma unroll
            for (int n = 0; n < 4; ++n)
                acc[m][n] = __builtin_amdgcn_mfma_f32_16x16x32_bf16(af[m], bfr[n], acc[m][n], 0, 0, 0);
        __syncthreads();
    }

    int cc = lane & 15, rq = (lane >> 4) * 4;
#pragma unroll
    for (int m = 0; m < 4; ++m) {
#pragma unroll
        for (int r = 0; r < 4; ++r) {
            int gr = row0 + wr * 64 + m * 16 + rq + r;
            if (gr >= M) continue;
            float ds = dscale ? dscale[gr] : 1.0f;
#pragma unroll
            for (int n = 0; n < 4; ++n) {
                int gc = col0 + wc * 64 + n * 16 + cc;
                float v = acc[m][n][r];
                if (bias) v += bias[gc];
                if (relu) v = fmaxf(v, 0.f);
                Cb[(size_t)gr * NC + gc] = f2bf(v * ds);
            }
        }
    }
}

// ---------------- aggregation: aout[v] = dinv[v] * sum_{s in padded list} hin'[s] ----------------
// hin' is pre-scaled by dinv (folded into producing GEMM). Lists padded to x8 with zero-row (NN).
// One wave per node; 8 independent 512B row-gathers in flight; wave-uniform index loads.

__global__ __launch_bounds__(256) void k_aggregate_bf(const ushort* __restrict__ hin,
                                                      const int* __restrict__ rowp,
                                                      const int* __restrict__ csrc,
                                                      const float* __restrict__ dinv,
                                                      ushort* __restrict__ aout, int n) {
    int wave = threadIdx.x >> 6, lane = threadIdx.x & 63;
    int node = blockIdx.x * 4 + wave;
    if (node >= n) return;
    int beg = __builtin_amdgcn_readfirstlane(rowp[node]);
    int end = __builtin_amdgcn_readfirstlane(rowp[node + 1]);
    const ushort* hc = hin + lane * 4;
    float4 acc = make_float4(0.f, 0.f, 0.f, 0.f);
    for (int j = beg; j < end; j += 8) {
        int s0 = csrc[j + 0], s1 = csrc[j + 1], s2 = csrc[j + 2], s3 = csrc[j + 3];
        int s4 = csrc[j + 4], s5 = csrc[j + 5], s6 = csrc[j + 6], s7 = csrc[j + 7];
        ushort4 r0 = *(const ushort4*)&hc[(size_t)s0 * HID];
        ushort4 r1 = *(const ushort4*)&hc[(size_t)s1 * HID];
        ushort4 r2 = *(const ushort4*)&hc[(size_t)s2 * HID];
        ushort4 r3 = *(const ushort4*)&hc[(size_t)s3 * HID];
        ushort4 r4 = *(const ushort4*)&hc[(size_t)s4 * HID];
        ushort4 r5 = *(const ushort4*)&hc[(size_t)s5 * HID];
        ushort4 r6 = *(const ushort4*)&hc[(size_t)s6 * HID];
        ushort4 r7 = *(const ushort4*)&hc[(size_t)s7 * HID];
        acc.x += ((bf2f(r0.x) + bf2f(r1.x)) + (bf2f(r2.x) + bf2f(r3.x))) +
                 ((bf2f(r4.x) + bf2f(r5.x)) + (bf2f(r6.x) + bf2f(r7.x)));
        acc.y += ((bf2f(r0.y) + bf2f(r1.y)) + (bf2f(r2.y) + bf2f(r3.y))) +
                 ((bf2f(r4.y) + bf2f(r5.y)) + (bf2f(r6.y) + bf2f(r7.y)));
        acc.z += ((bf2f(r0.z) + bf2f(r1.z)) + (bf2f(r2.z) + bf2f(r3.z))) +
                 ((bf2f(r4.z) + bf2f(r5.z)) + (bf2f(r6.z) + bf2f(r7.z)));
        acc.w += ((bf2f(r0.w) + bf2f(r1.w)) + (bf2f(r2.w) + bf2f(r3.w))) +
                 ((bf2f(r4.w) + bf2f(r5.w)) + (bf2f(r6.w) + bf2f(r7.w)));
    }
    float dn = dinv[node];
    ushort4 o;
    o.x = f2bf(dn * acc.x); o.y = f2bf(dn * acc.y);
    o.z = f2bf(dn * acc.z); o.w = f2bf(dn * acc.w);
    *(ushort4*)&aout[(size_t)node * HID + lane * 4] = o;
}

// ---------------- fused pool + projection + LayerNorm (one block per graph) ----------------

__global__ __launch_bounds__(256) void k_pool_proj_ln(const ushort* __restrict__ hbf, const int* __restrict__ gstart,
                                                      const float* __restrict__ Wp, const float* __restrict__ bp,
                                                      const float* __restrict__ gamma, const float* __restrict__ beta,
                                                      float* __restrict__ out) {
    __shared__ float mol[HID];
    __shared__ float part[4][NODE_DIM];
    int g = blockIdx.x;
    int t = threadIdx.x;
    int beg = gstart[g], end = gstart[g + 1];
    float sum = 0.f;
    for (int r = beg; r < end; ++r) sum += bf2f(hbf[(size_t)r * HID + t]);
    float inv = 1.0f / fmaxf((float)(end - beg), 1.0f);
    mol[t] = sum * inv;
    __syncthreads();
    int w = t >> 6, j = t & 63;
    float p = 0.f;
    int k0 = w * 64;
#pragma unroll 8
    for (int k = 0; k < 64; ++k) p += mol[k0 + k] * Wp[(size_t)(k0 + k) * NODE_DIM + j];
    part[w][j] = p;
    __syncthreads();
    if (t < 64) {
        float pj = part[0][j] + part[1][j] + part[2][j] + part[3][j] + bp[j];
        float s = pj;
#pragma unroll
        for (int m = 1; m < 64; m <<= 1) s += __shfl_xor(s, m);
        float mu = s * (1.0f / 64.0f);
        float d = pj - mu;
        float vs = d * d;
#pragma unroll
        for (int m = 1; m < 64; m <<= 1) vs += __shfl_xor(vs, m);
        out[(size_t)g * NODE_DIM + j] = d * rsqrtf(vs * (1.0f / 64.0f) + LN_EPS) * gamma[j] + beta[j];
    }
}

// ---------------- launch ----------------

extern "C" void kernel_launch(void* const* d_in, const int* in_sizes, int n_in,
                              void* d_out, int out_size, void* d_ws, size_t ws_size,
                              hipStream_t stream) {
    const float* x     = (const float*)d_in[0];
    const int*   ei    = (const int*)d_in[1];
    const int*   batch = (const int*)d_in[2];
    const float* W_enc = (const float*)d_in[3];
    const float* b_enc = (const float*)d_in[4];
    const float* Ws    = (const float*)d_in[5];
    const float* bs    = (const float*)d_in[6];
    const float* Wp    = (const float*)d_in[7];
    const float* bp    = (const float*)d_in[8];
    const float* gamma = (const float*)d_in[9];
    const float* beta  = (const float*)d_in[10];
    float* out = (float*)d_out;

    // workspace layout
    ushort* hbf  = (ushort*)d_ws;                        // (N+1)*HID bf16 (row N = zero row)
    ushort* abf  = hbf + (size_t)(NN + 1) * HID;         // N*HID bf16 (aggregated, dinv-prescaled)
    ushort* xbf  = abf + (size_t)NN * HID;               // N*ATOM_DIM bf16
    ushort* wtE  = xbf + (size_t)NN * ATOM_DIM;          // 256*128 (W_enc^T)
    ushort* wtL  = wtE + HID * ATOM_DIM;                 // 3 * 256*256 (Ws^T)
    float*  dinv = (float*)(wtL + (size_t)NUM_LAYERS * HID * HID);  // N
    int* cnt    = (int*)(dinv + NN);                     // N
    int* rowp   = cnt + NN;                              // N+1
    int* fill   = rowp + NN + 1;                         // N
    int* csrc   = fill + NN;                             // CSRC_CAP
    int* csum   = csrc + CSRC_CAP;                       // 64
    int* gstart = csum + 64;                             // G+1

    const int EN = EE + NN;
    const int NCH = (NN + 1023) / 1024;

    // fused prep: cvt + weight transposes + gbound + cnt zero + csrc prefill + zero row
    k_prep<<<PB_TOTAL, 256, 0, stream>>>(x, xbf, W_enc, wtE, Ws, wtL, batch, gstart,
                                         cnt, csrc, hbf + (size_t)NN * HID);

    // CSR build
    k_count<<<(EE + 255) / 256, 256, 0, stream>>>(ei, cnt, EE);
    k_scan1<<<NCH, 256, 0, stream>>>(cnt, rowp, csum, NN);
    k_scan2<<<NCH, 256, 0, stream>>>(rowp, fill, csum, cnt, dinv, NN);
    k_fill<<<(EN + 255) / 256, 256, 0, stream>>>(ei, fill, csrc, EE, NN);

    dim3 ggrid((NN + 127) / 128, HID / 128);

    // atom encoder: hbf = bf16( dinv * (x @ W_enc + b_enc) )   (dinv folded for next agg)
    k_gemm_bf16<<<ggrid, 256, 0, stream>>>(xbf, wtE, b_enc, hbf, dinv, 0, NN, ATOM_DIM, HID);

    // GCN layers: agg(h') then GEMM (+bias, relu, dinv-fold except last)
    for (int l = 0; l < NUM_LAYERS; ++l) {
        k_aggregate_bf<<<(NN + 3) / 4, 256, 0, stream>>>(hbf, rowp, csrc, dinv, abf, NN);
        const float* ds = (l < NUM_LAYERS - 1) ? dinv : nullptr;
        k_gemm_bf16<<<ggrid, 256, 0, stream>>>(abf, wtL + (size_t)l * HID * HID, bs + (size_t)l * HID,
                                               hbf, ds, 1, NN, HID, HID);
    }

    // fused global-mean-pool + projection + LayerNorm
    k_pool_proj_ln<<<GG, 256, 0, stream>>>(hbf, gstart, Wp, bp, gamma, beta, out);
}

// Round 7
// 298.563 us; speedup vs baseline: 2.6735x; 1.0222x over previous
//
#include <hip/hip_runtime.h>
#include <hip/hip_bf16.h>

#define NN 50000
#define EE 300000
#define ATOM_DIM 128
#define HID 256
#define NODE_DIM 64
#define NUM_LAYERS 3
#define GG 2000
#define LN_EPS 1e-5f
#define CSRC_CAP 704512   // >= E + 8*N (padded-to-8 bound = 700000)

typedef __attribute__((ext_vector_type(8))) short bf16x8;
typedef __attribute__((ext_vector_type(4))) float f32x4;

__device__ __forceinline__ ushort f2bf(float f) {
    __hip_bfloat16 h = __float2bfloat16(f);
    return *reinterpret_cast<ushort*>(&h);
}
__device__ __forceinline__ float bf2f(ushort u) {
    __hip_bfloat16 h = *reinterpret_cast<__hip_bfloat16*>(&u);
    return __bfloat162float(h);
}

__device__ __forceinline__ void gll16(const void* g, void* l) {
    __builtin_amdgcn_global_load_lds((const __attribute__((address_space(1))) unsigned int*)g,
                                     (__attribute__((address_space(3))) unsigned int*)l, 16, 0, 0);
}

// ---------------- fused prep kernel: branch ladder over flat grid ----------------
// segments: [cvt x][wt enc][wt layers][gbound][csrc prefill][cnt zero][hbf zero-row]

#define PB_CVT   6250   // 1.6M float4 (N*ATOM/4)
#define PB_WTE   32     // (256/32)*(128/32)
#define PB_WTL   192    // 64 * 3 layers
#define PB_GB    8      // 2001 threads
#define PB_CSRC  688    // 176128 int4
#define PB_CNT   49     // 12500 int4
#define PB_ZROW  1
#define PB_TOTAL (PB_CVT + PB_WTE + PB_WTL + PB_GB + PB_CSRC + PB_CNT + PB_ZROW)

__device__ __forceinline__ void wt_tile(const float* __restrict__ W, ushort* __restrict__ Wt,
                                        int K, int N, int bx, int by) {
    __shared__ float t[32][33];
    int lx = threadIdx.x & 31, ly = threadIdx.x >> 5;  // 32x8
#pragma unroll
    for (int s = 0; s < 32; s += 8)
        t[ly + s][lx] = W[(size_t)(by * 32 + ly + s) * N + bx * 32 + lx];
    __syncthreads();
#pragma unroll
    for (int s = 0; s < 32; s += 8)
        Wt[(size_t)(bx * 32 + ly + s) * K + by * 32 + lx] = f2bf(t[lx][ly + s]);
}

__global__ __launch_bounds__(256) void k_prep(const float* __restrict__ x, ushort* __restrict__ xbf,
                                              const float* __restrict__ W_enc, ushort* __restrict__ wtE,
                                              const float* __restrict__ Ws, ushort* __restrict__ wtL,
                                              const int* __restrict__ batch, int* __restrict__ gstart,
                                              int* __restrict__ cnt, int* __restrict__ csrc,
                                              ushort* __restrict__ hbf_zero_row) {
    int b = blockIdx.x;
    int tid = threadIdx.x;
    if (b < PB_CVT) {
        int i = (b * 256 + tid) * 4;
        float4 v = *(const float4*)&x[i];
        ushort4 o;
        o.x = f2bf(v.x); o.y = f2bf(v.y); o.z = f2bf(v.z); o.w = f2bf(v.w);
        *(ushort4*)&xbf[i] = o;
        return;
    }
    b -= PB_CVT;
    if (b < PB_WTE) {  // W_enc^T: K=128, N=256
        wt_tile(W_enc, wtE, ATOM_DIM, HID, b & 7, b >> 3);
        return;
    }
    b -= PB_WTE;
    if (b < PB_WTL) {  // Ws^T: 3 layers of 256x256
        int z = b >> 6, r = b & 63;
        wt_tile(Ws + (size_t)z * HID * HID, wtL + (size_t)z * HID * HID, HID, HID, r & 7, r >> 3);
        return;
    }
    b -= PB_WTL;
    if (b < PB_GB) {   // graph boundaries: lower_bound over sorted batch
        int g = b * 256 + tid;
        if (g > GG) return;
        int lo = 0, hi = NN;
        while (lo < hi) { int mid = (lo + hi) >> 1; if (batch[mid] < g) lo = mid + 1; else hi = mid; }
        gstart[g] = lo;
        return;
    }
    b -= PB_GB;
    if (b < PB_CSRC) { // prefill csrc with zero-row index NN
        int i = (b * 256 + tid) * 4;
        if (i < CSRC_CAP) *(int4*)&csrc[i] = make_int4(NN, NN, NN, NN);
        return;
    }
    b -= PB_CSRC;
    if (b < PB_CNT) {  // zero cnt
        int i = (b * 256 + tid) * 4;
        if (i < NN) *(int4*)&cnt[i] = make_int4(0, 0, 0, 0);
        return;
    }
    // zero row of hbf (row index NN)
    hbf_zero_row[tid] = 0;
}

// ---------------- CSR build ----------------

__global__ __launch_bounds__(256) void k_count(const int* __restrict__ ei, int* cnt, int e_total) {
    int e = blockIdx.x * 256 + threadIdx.x;
    if (e < e_total) atomicAdd(&cnt[ei[e_total + e]], 1);  // dst = ei[1][e]
}

// exclusive scan over padded counts ((cnt+1+7)&~7); chunk = 1024 per block
__global__ __launch_bounds__(256) void k_scan1(const int* __restrict__ cnt, int* __restrict__ rowp,
                                               int* __restrict__ csum, int n) {
    __shared__ int s[256];
    int tid = threadIdx.x;
    int base = blockIdx.x * 1024 + tid * 4;
    int v[4];
#pragma unroll
    for (int j = 0; j < 4; ++j) { int i = base + j; v[j] = (i < n) ? ((cnt[i] + 8) & ~7) : 0; }
    int tsum = v[0] + v[1] + v[2] + v[3];
    s[tid] = tsum;
    __syncthreads();
    for (int off = 1; off < 256; off <<= 1) {
        int t = (tid >= off) ? s[tid - off] : 0;
        __syncthreads();
        s[tid] += t;
        __syncthreads();
    }
    int excl = s[tid] - tsum;
#pragma unroll
    for (int j = 0; j < 4; ++j) { int i = base + j; if (i < n) rowp[i] = excl; excl += v[j]; }
    if (tid == 255) csum[blockIdx.x] = s[255];
}

// finalize scan; emit fill[] cursor and dinv[] = rsqrt(real degree)
__global__ __launch_bounds__(256) void k_scan2(int* __restrict__ rowp, int* __restrict__ fill,
                                               const int* __restrict__ csum, const int* __restrict__ cnt,
                                               float* __restrict__ dinv, int n) {
    __shared__ int soff;
    int chunk = blockIdx.x;
    if (threadIdx.x == 0) {
        int o = 0;
        for (int c = 0; c < chunk; ++c) o += csum[c];
        soff = o;
    }
    __syncthreads();
    int off = soff;
    int base = chunk * 1024 + threadIdx.x * 4;
#pragma unroll
    for (int j = 0; j < 4; ++j) {
        int i = base + j;
        if (i < n) {
            int r = rowp[i] + off;
            rowp[i] = r; fill[i] = r;
            dinv[i] = rsqrtf((float)(cnt[i] + 1));
        }
    }
    if (chunk == gridDim.x - 1 && threadIdx.x == 255) rowp[n] = off + csum[chunk];
}

__global__ __launch_bounds__(256) void k_fill(const int* __restrict__ ei, int* fill, int* __restrict__ csrc,
                                              int e_total, int n) {
    int e = blockIdx.x * 256 + threadIdx.x;
    int tot = e_total + n;
    if (e >= tot) return;
    int s, d;
    if (e < e_total) { s = ei[e]; d = ei[e_total + e]; }
    else { s = d = e - e_total; }
    int pos = atomicAdd(&fill[d], 1);
    csrc[pos] = s;
}

// ---------------- bf16 MFMA GEMM: Cb = opt_dscale( opt_relu(A @ Bt^T + bias) ) ----------------
// 128x128 tile, BK=32, 4 waves (2x2), each wave 64x64 = 4x4 frags of 16x16x32.
// 2-phase double-buffered pipeline (T3 minimum): STAGE(next) issued before COMPUTE(cur),
// one vmcnt(0)-draining __syncthreads() per K-tile.

__global__ __launch_bounds__(256) void k_gemm_bf16(const ushort* __restrict__ A, const ushort* __restrict__ Bt,
                                                   const float* __restrict__ bias, ushort* __restrict__ Cb,
                                                   const float* __restrict__ dscale, int relu,
                                                   int M, int K, int NC) {
    __shared__ short As[2][4096];  // [buf][128 rows x 32 bf16]
    __shared__ short Bs[2][4096];
    int tid = threadIdx.x;
    int lane = tid & 63, w = tid >> 6;
    int wr = w >> 1, wc = w & 1;
    int row0 = blockIdx.y * 128, col0 = blockIdx.x * 128;  // x = col: adjacent blocks share A slab

    f32x4 acc[4][4] = {};

    int r15 = lane & 15;
    int swz = ((r15 >> 1) & 3) << 3;
    int koff = ((lane >> 4) << 3) ^ swz;

    // staging geometry; per-thread global base pointers (k0 added per step)
    const ushort* aB[2];
    const ushort* bB[2];
#pragma unroll
    for (int i = 0; i < 2; ++i) {
        int row = i * 64 + (tid >> 2);
        int cg = (tid & 3) ^ ((row >> 1) & 3);
        int ra = row0 + row; if (ra > M - 1) ra = M - 1;
        aB[i] = A + (size_t)ra * K + cg * 8;
        bB[i] = Bt + (size_t)(col0 + row) * K + cg * 8;
    }
    int ldst = w * 512;  // wave-uniform LDS dest offset (shorts) within each 2048 half

#define STAGE(buf, kk) do { int k0_ = (kk) << 5;                      \
        gll16(aB[0] + k0_, &As[buf][ldst]);                           \
        gll16(aB[1] + k0_, &As[buf][2048 + ldst]);                    \
        gll16(bB[0] + k0_, &Bs[buf][ldst]);                           \
        gll16(bB[1] + k0_, &Bs[buf][2048 + ldst]);                    \
    } while (0)

#define COMPUTE(buf) do {                                                              \
        bf16x8 af[4], bfr[4];                                                          \
        _Pragma("unroll")                                                              \
        for (int m = 0; m < 4; ++m)                                                    \
            af[m] = *(const bf16x8*)&As[buf][(wr * 64 + m * 16 + r15) * 32 + koff];    \
        _Pragma("unroll")                                                              \
        for (int n = 0; n < 4; ++n)                                                    \
            bfr[n] = *(const bf16x8*)&Bs[buf][(wc * 64 + n * 16 + r15) * 32 + koff];   \
        _Pragma("unroll")                                                              \
        for (int m = 0; m < 4; ++m)                                                    \
            _Pragma("unroll")                                                          \
            for (int n = 0; n < 4; ++n)                                                \
                acc[m][n] = __builtin_amdgcn_mfma_f32_16x16x32_bf16(af[m], bfr[n], acc[m][n], 0, 0, 0); \
    } while (0)

    int nk = K >> 5;
    STAGE(0, 0);
    __syncthreads();
    for (int t = 0; t < nk - 1; ++t) {
        int buf = t & 1;
        STAGE(buf ^ 1, t + 1);   // overlap next-tile HBM latency with this tile's MFMA
        COMPUTE(buf);
        __syncthreads();         // drains vmcnt(0): next buf ready, this buf consumed
    }
    COMPUTE((nk - 1) & 1);

#undef STAGE
#undef COMPUTE

    int cc = lane & 15, rq = (lane >> 4) * 4;
#pragma unroll
    for (int m = 0; m < 4; ++m) {
#pragma unroll
        for (int r = 0; r < 4; ++r) {
            int gr = row0 + wr * 64 + m * 16 + rq + r;
            if (gr >= M) continue;
            float ds = dscale ? dscale[gr] : 1.0f;
#pragma unroll
            for (int n = 0; n < 4; ++n) {
                int gc = col0 + wc * 64 + n * 16 + cc;
                float v = acc[m][n][r];
                if (bias) v += bias[gc];
                if (relu) v = fmaxf(v, 0.f);
                Cb[(size_t)gr * NC + gc] = f2bf(v * ds);
            }
        }
    }
}

// ---------------- aggregation: aout[v] = dinv[v] * sum_{s in padded list} hin'[s] ----------------
// hin' is pre-scaled by dinv (folded into producing GEMM). Lists padded to x8 with zero-row (NN).

__global__ __launch_bounds__(256) void k_aggregate_bf(const ushort* __restrict__ hin,
                                                      const int* __restrict__ rowp,
                                                      const int* __restrict__ csrc,
                                                      const float* __restrict__ dinv,
                                                      ushort* __restrict__ aout, int n) {
    int wave = threadIdx.x >> 6, lane = threadIdx.x & 63;
    int node = blockIdx.x * 4 + wave;
    if (node >= n) return;
    int beg = __builtin_amdgcn_readfirstlane(rowp[node]);
    int end = __builtin_amdgcn_readfirstlane(rowp[node + 1]);
    const ushort* hc = hin + lane * 4;
    float4 acc = make_float4(0.f, 0.f, 0.f, 0.f);
    for (int j = beg; j < end; j += 8) {
        int s0 = csrc[j + 0], s1 = csrc[j + 1], s2 = csrc[j + 2], s3 = csrc[j + 3];
        int s4 = csrc[j + 4], s5 = csrc[j + 5], s6 = csrc[j + 6], s7 = csrc[j + 7];
        ushort4 r0 = *(const ushort4*)&hc[(size_t)s0 * HID];
        ushort4 r1 = *(const ushort4*)&hc[(size_t)s1 * HID];
        ushort4 r2 = *(const ushort4*)&hc[(size_t)s2 * HID];
        ushort4 r3 = *(const ushort4*)&hc[(size_t)s3 * HID];
        ushort4 r4 = *(const ushort4*)&hc[(size_t)s4 * HID];
        ushort4 r5 = *(const ushort4*)&hc[(size_t)s5 * HID];
        ushort4 r6 = *(const ushort4*)&hc[(size_t)s6 * HID];
        ushort4 r7 = *(const ushort4*)&hc[(size_t)s7 * HID];
        acc.x += ((bf2f(r0.x) + bf2f(r1.x)) + (bf2f(r2.x) + bf2f(r3.x))) +
                 ((bf2f(r4.x) + bf2f(r5.x)) + (bf2f(r6.x) + bf2f(r7.x)));
        acc.y += ((bf2f(r0.y) + bf2f(r1.y)) + (bf2f(r2.y) + bf2f(r3.y))) +
                 ((bf2f(r4.y) + bf2f(r5.y)) + (bf2f(r6.y) + bf2f(r7.y)));
        acc.z += ((bf2f(r0.z) + bf2f(r1.z)) + (bf2f(r2.z) + bf2f(r3.z))) +
                 ((bf2f(r4.z) + bf2f(r5.z)) + (bf2f(r6.z) + bf2f(r7.z)));
        acc.w += ((bf2f(r0.w) + bf2f(r1.w)) + (bf2f(r2.w) + bf2f(r3.w))) +
                 ((bf2f(r4.w) + bf2f(r5.w)) + (bf2f(r6.w) + bf2f(r7.w)));
    }
    float dn = dinv[node];
    ushort4 o;
    o.x = f2bf(dn * acc.x); o.y = f2bf(dn * acc.y);
    o.z = f2bf(dn * acc.z); o.w = f2bf(dn * acc.w);
    *(ushort4*)&aout[(size_t)node * HID + lane * 4] = o;
}

// ---------------- fused pool + projection + LayerNorm (one block per graph) ----------------

__global__ __launch_bounds__(256) void k_pool_proj_ln(const ushort* __restrict__ hbf, const int* __restrict__ gstart,
                                                      const float* __restrict__ Wp, const float* __restrict__ bp,
                                                      const float* __restrict__ gamma, const float* __restrict__ beta,
                                                      float* __restrict__ out) {
    __shared__ float mol[HID];
    __shared__ float part[4][NODE_DIM];
    int g = blockIdx.x;
    int t = threadIdx.x;
    int beg = gstart[g], end = gstart[g + 1];
    float sum = 0.f;
    for (int r = beg; r < end; ++r) sum += bf2f(hbf[(size_t)r * HID + t]);
    float inv = 1.0f / fmaxf((float)(end - beg), 1.0f);
    mol[t] = sum * inv;
    __syncthreads();
    int w = t >> 6, j = t & 63;
    float p = 0.f;
    int k0 = w * 64;
#pragma unroll 8
    for (int k = 0; k < 64; ++k) p += mol[k0 + k] * Wp[(size_t)(k0 + k) * NODE_DIM + j];
    part[w][j] = p;
    __syncthreads();
    if (t < 64) {
        float pj = part[0][j] + part[1][j] + part[2][j] + part[3][j] + bp[j];
        float s = pj;
#pragma unroll
        for (int m = 1; m < 64; m <<= 1) s += __shfl_xor(s, m);
        float mu = s * (1.0f / 64.0f);
        float d = pj - mu;
        float vs = d * d;
#pragma unroll
        for (int m = 1; m < 64; m <<= 1) vs += __shfl_xor(vs, m);
        out[(size_t)g * NODE_DIM + j] = d * rsqrtf(vs * (1.0f / 64.0f) + LN_EPS) * gamma[j] + beta[j];
    }
}

// ---------------- launch ----------------

extern "C" void kernel_launch(void* const* d_in, const int* in_sizes, int n_in,
                              void* d_out, int out_size, void* d_ws, size_t ws_size,
                              hipStream_t stream) {
    const float* x     = (const float*)d_in[0];
    const int*   ei    = (const int*)d_in[1];
    const int*   batch = (const int*)d_in[2];
    const float* W_enc = (const float*)d_in[3];
    const float* b_enc = (const float*)d_in[4];
    const float* Ws    = (const float*)d_in[5];
    const float* bs    = (const float*)d_in[6];
    const float* Wp    = (const float*)d_in[7];
    const float* bp    = (const float*)d_in[8];
    const float* gamma = (const float*)d_in[9];
    const float* beta  = (const float*)d_in[10];
    float* out = (float*)d_out;

    // workspace layout
    ushort* hbf  = (ushort*)d_ws;                        // (N+1)*HID bf16 (row N = zero row)
    ushort* abf  = hbf + (size_t)(NN + 1) * HID;         // N*HID bf16 (aggregated, dinv-prescaled)
    ushort* xbf  = abf + (size_t)NN * HID;               // N*ATOM_DIM bf16
    ushort* wtE  = xbf + (size_t)NN * ATOM_DIM;          // 256*128 (W_enc^T)
    ushort* wtL  = wtE + HID * ATOM_DIM;                 // 3 * 256*256 (Ws^T)
    float*  dinv = (float*)(wtL + (size_t)NUM_LAYERS * HID * HID);  // N
    int* cnt    = (int*)(dinv + NN);                     // N
    int* rowp   = cnt + NN;                              // N+1
    int* fill   = rowp + NN + 1;                         // N
    int* csrc   = fill + NN;                             // CSRC_CAP
    int* csum   = csrc + CSRC_CAP;                       // 64
    int* gstart = csum + 64;                             // G+1

    const int EN = EE + NN;
    const int NCH = (NN + 1023) / 1024;

    // fused prep: cvt + weight transposes + gbound + cnt zero + csrc prefill + zero row
    k_prep<<<PB_TOTAL, 256, 0, stream>>>(x, xbf, W_enc, wtE, Ws, wtL, batch, gstart,
                                         cnt, csrc, hbf + (size_t)NN * HID);

    // CSR build
    k_count<<<(EE + 255) / 256, 256, 0, stream>>>(ei, cnt, EE);
    k_scan1<<<NCH, 256, 0, stream>>>(cnt, rowp, csum, NN);
    k_scan2<<<NCH, 256, 0, stream>>>(rowp, fill, csum, cnt, dinv, NN);
    k_fill<<<(EN + 255) / 256, 256, 0, stream>>>(ei, fill, csrc, EE, NN);

    dim3 ggrid(HID / 128, (NN + 127) / 128);  // x = col-tiles (adjacent blocks share A slab)

    // atom encoder: hbf = bf16( dinv * (x @ W_enc + b_enc) )   (dinv folded for next agg)
    k_gemm_bf16<<<ggrid, 256, 0, stream>>>(xbf, wtE, b_enc, hbf, dinv, 0, NN, ATOM_DIM, HID);

    // GCN layers: agg(h') then GEMM (+bias, relu, dinv-fold except last)
    for (int l = 0; l < NUM_LAYERS; ++l) {
        k_aggregate_bf<<<(NN + 3) / 4, 256, 0, stream>>>(hbf, rowp, csrc, dinv, abf, NN);
        const float* ds = (l < NUM_LAYERS - 1) ? dinv : nullptr;
        k_gemm_bf16<<<ggrid, 256, 0, stream>>>(abf, wtL + (size_t)l * HID * HID, bs + (size_t)l * HID,
                                               hbf, ds, 1, NN, HID, HID);
    }

    // fused global-mean-pool + projection + LayerNorm
    k_pool_proj_ln<<<GG, 256, 0, stream>>>(hbf, gstart, Wp, bp, gamma, beta, out);
}